// Round 1
// baseline (718.127 us; speedup 1.0000x reference)
//
#include <hip/hip_runtime.h>

// GAT 2-layer forward for MI355X.
// Strategy:
//  - Build CSR (by dst) once per call: histogram + 2-level scan + atomic fill.
//  - Layer kernels: fused GEMM+attention-logits, then per-node gather-aggregate
//    (softmax denominators folded in: out = sum(w*h[src]) / (sum(w)+eps)).
//  - Softmax max-subtraction omitted (shift-invariant, logits bounded ~|8|).

static __device__ __forceinline__ float lrelu(float x) { return x > 0.f ? x : 0.2f * x; }

// ---------------- CSR build ----------------
__global__ void count_deg(const int* __restrict__ dstv, int* __restrict__ deg, int E) {
  int e = blockIdx.x * blockDim.x + threadIdx.x;
  if (e < E) atomicAdd(&deg[dstv[e]], 1);
}

__global__ void scan_partial(const int* __restrict__ deg, int* __restrict__ off,
                             int* __restrict__ bsum, int n) {
  int tid = threadIdx.x;
  int i = blockIdx.x * 256 + tid;
  int v = (i < n) ? deg[i] : 0;
  int lane = tid & 63, w = tid >> 6;
  int sv = v;
#pragma unroll
  for (int o = 1; o < 64; o <<= 1) {
    int t = __shfl_up(sv, o);
    if (lane >= o) sv += t;
  }
  __shared__ int ws[4];
  if (lane == 63) ws[w] = sv;
  __syncthreads();
  int add = 0;
  for (int j = 0; j < w; ++j) add += ws[j];
  sv += add;
  if (i < n) off[i + 1] = sv;
  if (tid == 255) bsum[blockIdx.x] = sv;
}

__global__ void scan_bsum(int* __restrict__ bsum, int* __restrict__ off, int nb) {
  int tid = threadIdx.x;  // 256 threads; requires nb <= 256 (N=50000 -> nb=196)
  int v = (tid < nb) ? bsum[tid] : 0;
  int lane = tid & 63, w = tid >> 6;
  int sv = v;
#pragma unroll
  for (int o = 1; o < 64; o <<= 1) {
    int t = __shfl_up(sv, o);
    if (lane >= o) sv += t;
  }
  __shared__ int ws[4];
  if (lane == 63) ws[w] = sv;
  __syncthreads();
  int add = 0;
  for (int j = 0; j < w; ++j) add += ws[j];
  sv += add;
  if (tid < nb) bsum[tid] = sv - v;  // exclusive prefix of block sums
  if (tid == 0) off[0] = 0;
}

__global__ void add_carry(const int* __restrict__ deg, int* __restrict__ off,
                          const int* __restrict__ bsum, int* __restrict__ cur, int n) {
  int i = blockIdx.x * 256 + threadIdx.x;
  if (i < n) {
    int o = off[i + 1] + bsum[blockIdx.x];
    off[i + 1] = o;
    cur[i] = o - deg[i];  // = off[i]
  }
}

__global__ void fill_csr(const int* __restrict__ srcv, const int* __restrict__ dstv,
                         int* __restrict__ cur, int* __restrict__ csr, int E) {
  int e = blockIdx.x * blockDim.x + threadIdx.x;
  if (e < E) {
    int p = atomicAdd(&cur[dstv[e]], 1);
    csr[p] = srcv[e];
  }
}

// ---------------- Layer 1: GEMM [n,128]x[128,256] + per-node logits ----------------
#define G1_ROWS 8
__global__ __launch_bounds__(256) void gemm1(const float* __restrict__ x, const float* __restrict__ W,
                                             const float* __restrict__ a_src, const float* __restrict__ a_dst,
                                             float* __restrict__ h, float* __restrict__ al_src,
                                             float* __restrict__ al_dst, int n) {
  __shared__ float Wt[256][132];      // W^T [col][k], +4 pad keeps b128 16B-aligned & banks spread
  __shared__ float xs[G1_ROWS][128];  // staged input rows (broadcast reads)
  int tid = threadIdx.x;
  for (int idx = tid; idx < 128 * 256; idx += 256) {
    int k = idx >> 8, c = idx & 255;
    Wt[c][k] = W[idx];
  }
  float as = a_src[tid];  // a[h][c], flat index == col
  float ad = a_dst[tid];
  int head = tid >> 5;
  for (int r0 = blockIdx.x * G1_ROWS; r0 < n; r0 += gridDim.x * G1_ROWS) {
    __syncthreads();
    for (int idx = tid; idx < G1_ROWS * 128; idx += 256) {
      int r = idx >> 7, k = idx & 127;
      int rr = r0 + r;
      xs[r][k] = (rr < n) ? x[rr * 128 + k] : 0.f;
    }
    __syncthreads();
    float acc[G1_ROWS];
#pragma unroll
    for (int r = 0; r < G1_ROWS; ++r) acc[r] = 0.f;
    for (int k = 0; k < 128; k += 4) {
      float4 w4 = *(const float4*)&Wt[tid][k];
#pragma unroll
      for (int r = 0; r < G1_ROWS; ++r) {
        float4 x4 = *(const float4*)&xs[r][k];
        acc[r] += w4.x * x4.x;
        acc[r] += w4.y * x4.y;
        acc[r] += w4.z * x4.z;
        acc[r] += w4.w * x4.w;
      }
    }
#pragma unroll
    for (int r = 0; r < G1_ROWS; ++r) {
      int rr = r0 + r;
      if (rr < n) {
        h[rr * 256 + tid] = acc[r];
        float vs = acc[r] * as;
        float vd = acc[r] * ad;
#pragma unroll
        for (int o = 16; o >= 1; o >>= 1) {  // reduce within 32-lane head group
          vs += __shfl_xor(vs, o);
          vd += __shfl_xor(vd, o);
        }
        if ((tid & 31) == 0) {
          al_src[rr * 8 + head] = vs;
          al_dst[rr * 8 + head] = vd;
        }
      }
    }
  }
}

// ---------------- Layer 1 aggregation: one block (256 thr) per dst node ----------------
__global__ __launch_bounds__(256) void agg1(const float* __restrict__ h, const float* __restrict__ al_src,
                                            const float* __restrict__ al_dst, const int* __restrict__ off,
                                            const int* __restrict__ csr, const float* __restrict__ bias,
                                            float* __restrict__ outp, int n) {
  int d = blockIdx.x;
  int tid = threadIdx.x;
  int head = tid >> 5;
  float ad = al_dst[d * 8 + head];
  // self loop
  float w0 = expf(lrelu(al_src[d * 8 + head] + ad));
  float acc = w0 * h[d * 256 + tid];
  float wsum = w0;
  int beg = off[d], end = off[d + 1];
  for (int i = beg; i < end; ++i) {
    int s = csr[i];
    float w = expf(lrelu(al_src[s * 8 + head] + ad));
    acc += w * h[s * 256 + tid];
    wsum += w;
  }
  float v = acc / (wsum + 1e-16f) + bias[tid];
  outp[d * 256 + tid] = v > 0.f ? v : expm1f(v);  // ELU fused
}

// ---------------- Layer 2: GEMM [n,256]x[256,64] + logits ----------------
__global__ __launch_bounds__(256) void gemm2(const float* __restrict__ xin, const float* __restrict__ W,
                                             const float* __restrict__ a_src, const float* __restrict__ a_dst,
                                             float* __restrict__ h, float* __restrict__ al_src,
                                             float* __restrict__ al_dst, int n) {
  __shared__ float Wt[64][260];  // W^T [col][k], pad 4
  __shared__ float xs[8][256];
  int tid = threadIdx.x;
  int c = tid & 63, ro = tid >> 6;
  for (int idx = tid; idx < 256 * 64; idx += 256) {
    int k = idx >> 6, cc = idx & 63;
    Wt[cc][k] = W[idx];
  }
  float as = a_src[c];
  float ad = a_dst[c];
  for (int r0 = blockIdx.x * 8; r0 < n; r0 += gridDim.x * 8) {
    __syncthreads();
    for (int idx = tid; idx < 8 * 256; idx += 256) {
      int r = idx >> 8, k = idx & 255;
      int rr = r0 + r;
      xs[r][k] = (rr < n) ? xin[rr * 256 + k] : 0.f;
    }
    __syncthreads();
    float acc0 = 0.f, acc1 = 0.f;
    for (int k = 0; k < 256; k += 4) {
      float4 w4 = *(const float4*)&Wt[c][k];
      float4 x0 = *(const float4*)&xs[ro][k];
      float4 x1 = *(const float4*)&xs[ro + 4][k];
      acc0 += w4.x * x0.x; acc0 += w4.y * x0.y; acc0 += w4.z * x0.z; acc0 += w4.w * x0.w;
      acc1 += w4.x * x1.x; acc1 += w4.y * x1.y; acc1 += w4.z * x1.z; acc1 += w4.w * x1.w;
    }
    int r_a = r0 + ro, r_b = r0 + ro + 4;
    if (r_a < n) {
      h[r_a * 64 + c] = acc0;
      float vs = acc0 * as, vd = acc0 * ad;
#pragma unroll
      for (int o = 32; o >= 1; o >>= 1) { vs += __shfl_xor(vs, o); vd += __shfl_xor(vd, o); }
      if (c == 0) { al_src[r_a] = vs; al_dst[r_a] = vd; }
    }
    if (r_b < n) {
      h[r_b * 64 + c] = acc1;
      float vs = acc1 * as, vd = acc1 * ad;
#pragma unroll
      for (int o = 32; o >= 1; o >>= 1) { vs += __shfl_xor(vs, o); vd += __shfl_xor(vd, o); }
      if (c == 0) { al_src[r_b] = vs; al_dst[r_b] = vd; }
    }
  }
}

// ---------------- Layer 2 aggregation: one wave per dst node, 4 nodes/block ----------------
__global__ __launch_bounds__(256) void agg2(const float* __restrict__ h, const float* __restrict__ al_src,
                                            const float* __restrict__ al_dst, const int* __restrict__ off,
                                            const int* __restrict__ csr, const float* __restrict__ bias,
                                            float* __restrict__ outp, int n) {
  int d = blockIdx.x * 4 + (threadIdx.x >> 6);
  int c = threadIdx.x & 63;
  if (d >= n) return;
  float ad = al_dst[d];
  float w0 = expf(lrelu(al_src[d] + ad));
  float acc = w0 * h[d * 64 + c];
  float wsum = w0;
  int beg = off[d], end = off[d + 1];
  for (int i = beg; i < end; ++i) {
    int s = csr[i];
    float w = expf(lrelu(al_src[s] + ad));
    acc += w * h[s * 64 + c];
    wsum += w;
  }
  outp[d * 64 + c] = acc / (wsum + 1e-16f) + bias[c];  // heads=1 -> mean is identity
}

extern "C" void kernel_launch(void* const* d_in, const int* in_sizes, int n_in,
                              void* d_out, int out_size, void* d_ws, size_t ws_size,
                              hipStream_t stream) {
  const float* x  = (const float*)d_in[0];
  const int* ei   = (const int*)d_in[1];
  const float* W1 = (const float*)d_in[2];
  const float* a1s = (const float*)d_in[3];
  const float* a1d = (const float*)d_in[4];
  const float* b1  = (const float*)d_in[5];
  const float* W2  = (const float*)d_in[6];
  const float* a2s = (const float*)d_in[7];
  const float* a2d = (const float*)d_in[8];
  const float* b2  = (const float*)d_in[9];
  float* outp = (float*)d_out;

  int n = in_sizes[0] / 128;   // 50000
  int E = in_sizes[1] / 2;     // 640000
  const int* srcv = ei;
  const int* dstv = ei + E;

  char* wsb = (char*)d_ws;
  size_t p = 0;
  auto alloc = [&](size_t bytes) -> char* {
    char* r = wsb + p;
    p += (bytes + 511) & ~size_t(511);
    return r;
  };
  int* deg  = (int*)alloc((size_t)n * 4);
  int* off  = (int*)alloc(((size_t)n + 1) * 4);
  int* cur  = (int*)alloc((size_t)n * 4);
  int* bsum = (int*)alloc(1024);
  int* csr  = (int*)alloc((size_t)E * 4);
  float* h1   = (float*)alloc((size_t)n * 256 * 4);
  float* al1s = (float*)alloc((size_t)n * 8 * 4);
  float* al1d = (float*)alloc((size_t)n * 8 * 4);
  float* o1   = (float*)alloc((size_t)n * 256 * 4);
  float* h2   = (float*)alloc((size_t)n * 64 * 4);
  float* al2s = (float*)alloc((size_t)n * 4);
  float* al2d = (float*)alloc((size_t)n * 4);
  (void)ws_size;

  hipMemsetAsync(deg, 0, (size_t)n * 4, stream);
  int eb = (E + 255) / 256;
  int nb = (n + 255) / 256;
  count_deg<<<eb, 256, 0, stream>>>(dstv, deg, E);
  scan_partial<<<nb, 256, 0, stream>>>(deg, off, bsum, n);
  scan_bsum<<<1, 256, 0, stream>>>(bsum, off, nb);
  add_carry<<<nb, 256, 0, stream>>>(deg, off, bsum, cur, n);
  fill_csr<<<eb, 256, 0, stream>>>(srcv, dstv, cur, csr, E);

  gemm1<<<256, 256, 0, stream>>>(x, W1, a1s, a1d, h1, al1s, al1d, n);
  agg1<<<n, 256, 0, stream>>>(h1, al1s, al1d, off, csr, b1, o1, n);
  gemm2<<<256, 256, 0, stream>>>(o1, W2, a2s, a2d, h2, al2s, al2d, n);
  agg2<<<(n + 3) / 4, 256, 0, stream>>>(h2, al2s, al2d, off, csr, b2, outp, n);
}

// Round 6
// 445.057 us; speedup vs baseline: 1.6136x; 1.6136x over previous
//
#include <hip/hip_runtime.h>

// GAT 2-layer forward for MI355X.
//  - CSR build (histogram + scan + fill), once per call.
//  - Register-tiled f32 GEMMs (8x8 / 8x4 per thread, k-chunk 32, ~VALU-bound).
//  - Small logit kernels (bandwidth-bound).
//  - Gather-aggregate per dst node, 2-way pipelined edge loop; softmax
//    normalization folded to a final divide (max-subtraction omitted:
//    shift-invariant, logits bounded ~|8|).

static __device__ __forceinline__ float lrelu(float x) { return x > 0.f ? x : 0.2f * x; }

// ---------------- CSR build ----------------
__global__ void count_deg(const int* __restrict__ dstv, int* __restrict__ deg, int E) {
  int e = blockIdx.x * blockDim.x + threadIdx.x;
  if (e < E) atomicAdd(&deg[dstv[e]], 1);
}

__global__ void scan_partial(const int* __restrict__ deg, int* __restrict__ off,
                             int* __restrict__ bsum, int n) {
  int tid = threadIdx.x;
  int i = blockIdx.x * 256 + tid;
  int v = (i < n) ? deg[i] : 0;
  int lane = tid & 63, w = tid >> 6;
  int sv = v;
#pragma unroll
  for (int o = 1; o < 64; o <<= 1) {
    int t = __shfl_up(sv, o);
    if (lane >= o) sv += t;
  }
  __shared__ int ws[4];
  if (lane == 63) ws[w] = sv;
  __syncthreads();
  int add = 0;
  for (int j = 0; j < w; ++j) add += ws[j];
  sv += add;
  if (i < n) off[i + 1] = sv;
  if (tid == 255) bsum[blockIdx.x] = sv;
}

__global__ void scan_bsum(int* __restrict__ bsum, int* __restrict__ off, int nb) {
  int tid = threadIdx.x;  // 256 threads; requires nb <= 256 (N=50000 -> nb=196)
  int v = (tid < nb) ? bsum[tid] : 0;
  int lane = tid & 63, w = tid >> 6;
  int sv = v;
#pragma unroll
  for (int o = 1; o < 64; o <<= 1) {
    int t = __shfl_up(sv, o);
    if (lane >= o) sv += t;
  }
  __shared__ int ws[4];
  if (lane == 63) ws[w] = sv;
  __syncthreads();
  int add = 0;
  for (int j = 0; j < w; ++j) add += ws[j];
  sv += add;
  if (tid < nb) bsum[tid] = sv - v;  // exclusive prefix of block sums
  if (tid == 0) off[0] = 0;
}

__global__ void add_carry(const int* __restrict__ deg, int* __restrict__ off,
                          const int* __restrict__ bsum, int* __restrict__ cur, int n) {
  int i = blockIdx.x * 256 + threadIdx.x;
  if (i < n) {
    int o = off[i + 1] + bsum[blockIdx.x];
    off[i + 1] = o;
    cur[i] = o - deg[i];  // = off[i]
  }
}

__global__ void fill_csr(const int* __restrict__ srcv, const int* __restrict__ dstv,
                         int* __restrict__ cur, int* __restrict__ csr, int E) {
  int e = blockIdx.x * blockDim.x + threadIdx.x;
  if (e < E) {
    int p = atomicAdd(&cur[dstv[e]], 1);
    csr[p] = srcv[e];
  }
}

// ---------------- GEMM1: [n,128] x [128,256] -> h1, tile 64x256, thread 8x8 ----------------
__global__ __launch_bounds__(256) void gemm1(const float* __restrict__ x, const float* __restrict__ W,
                                             float* __restrict__ h, int n) {
  __shared__ float xs[32][64];   // transposed: xs[k][row]; read=broadcast b128, write bank=row (free)
  __shared__ float Ws[32][256];  // Ws[k][col]; read b32 one-lane-per-bank (free)
  int tid = threadIdx.x;
  int tc = tid & 31;        // owns cols tc + 32*j, j=0..7 (one col per head)
  int tr = tid >> 5;        // owns rows r0 + tr*8 .. +7
  int lr = tid & 63, lj = tid >> 6;  // x-stage coords
  int r0 = blockIdx.x * 64;

  float acc[8][8];
#pragma unroll
  for (int r = 0; r < 8; ++r)
#pragma unroll
    for (int j = 0; j < 8; ++j) acc[r][j] = 0.f;

  for (int k0 = 0; k0 < 128; k0 += 32) {
    __syncthreads();
    // stage x chunk: 64 rows x 32 k
    {
      int rr = r0 + lr;
      float4 v0 = {0, 0, 0, 0}, v1 = {0, 0, 0, 0};
      if (rr < n) {
        const float* p = x + (size_t)rr * 128 + k0 + lj * 8;
        v0 = *(const float4*)p;
        v1 = *(const float4*)(p + 4);
      }
      int kk = lj * 8;
      xs[kk + 0][lr] = v0.x; xs[kk + 1][lr] = v0.y; xs[kk + 2][lr] = v0.z; xs[kk + 3][lr] = v0.w;
      xs[kk + 4][lr] = v1.x; xs[kk + 5][lr] = v1.y; xs[kk + 6][lr] = v1.z; xs[kk + 7][lr] = v1.w;
    }
    // stage W chunk: 32 x 256 floats, flat float4 copy
    {
      const float4* src = (const float4*)(W + (size_t)k0 * 256);
      float4* dst = (float4*)&Ws[0][0];
#pragma unroll
      for (int i = tid; i < 2048; i += 256) dst[i] = src[i];
    }
    __syncthreads();
#pragma unroll 4
    for (int k = 0; k < 32; ++k) {
      float xv[8];
      *(float4*)&xv[0] = *(const float4*)&xs[k][tr * 8];
      *(float4*)&xv[4] = *(const float4*)&xs[k][tr * 8 + 4];
      float wv[8];
#pragma unroll
      for (int j = 0; j < 8; ++j) wv[j] = Ws[k][tc + 32 * j];
#pragma unroll
      for (int r = 0; r < 8; ++r)
#pragma unroll
        for (int j = 0; j < 8; ++j) acc[r][j] = fmaf(xv[r], wv[j], acc[r][j]);
    }
  }
#pragma unroll
  for (int r = 0; r < 8; ++r) {
    int row = r0 + tr * 8 + r;
    if (row < n) {
#pragma unroll
      for (int j = 0; j < 8; ++j) h[(size_t)row * 256 + tc + 32 * j] = acc[r][j];
    }
  }
}

// ---------------- GEMM2: [n,256] x [256,64] -> h2, tile 128x64, thread 8x4 ----------------
__global__ __launch_bounds__(256) void gemm2(const float* __restrict__ xin, const float* __restrict__ W,
                                             float* __restrict__ h, int n) {
  __shared__ float xs[32][128];  // transposed
  __shared__ float Ws[32][64];
  int tid = threadIdx.x;
  int tc = tid & 15;  // owns cols tc + 16*j, j=0..3
  int tr = tid >> 4;  // owns rows r0 + tr*8 .. +7 (tr 0..15 -> 128 rows)
  int r0 = blockIdx.x * 128;

  float acc[8][4];
#pragma unroll
  for (int r = 0; r < 8; ++r)
#pragma unroll
    for (int j = 0; j < 4; ++j) acc[r][j] = 0.f;

  for (int k0 = 0; k0 < 256; k0 += 32) {
    __syncthreads();
    // stage x chunk: 128 rows x 32 k  (1024 float4s)
#pragma unroll
    for (int idx = tid; idx < 1024; idx += 256) {
      int r = idx & 127, q = idx >> 7;
      int rr = r0 + r;
      float4 v = {0, 0, 0, 0};
      if (rr < n) v = *(const float4*)(xin + (size_t)rr * 256 + k0 + q * 4);
      int kk = q * 4;
      xs[kk + 0][r] = v.x; xs[kk + 1][r] = v.y; xs[kk + 2][r] = v.z; xs[kk + 3][r] = v.w;
    }
    // stage W chunk: 32 x 64 floats (512 float4s)
    {
      const float4* src = (const float4*)(W + (size_t)k0 * 64);
      float4* dst = (float4*)&Ws[0][0];
#pragma unroll
      for (int i = tid; i < 512; i += 256) dst[i] = src[i];
    }
    __syncthreads();
#pragma unroll 4
    for (int k = 0; k < 32; ++k) {
      float xv[8];
      *(float4*)&xv[0] = *(const float4*)&xs[k][tr * 8];
      *(float4*)&xv[4] = *(const float4*)&xs[k][tr * 8 + 4];
      float wv[4];
#pragma unroll
      for (int j = 0; j < 4; ++j) wv[j] = Ws[k][tc + 16 * j];
#pragma unroll
      for (int r = 0; r < 8; ++r)
#pragma unroll
        for (int j = 0; j < 4; ++j) acc[r][j] = fmaf(xv[r], wv[j], acc[r][j]);
    }
  }
#pragma unroll
  for (int r = 0; r < 8; ++r) {
    int row = r0 + tr * 8 + r;
    if (row < n) {
#pragma unroll
      for (int j = 0; j < 4; ++j) h[(size_t)row * 64 + tc + 16 * j] = acc[r][j];
    }
  }
}

// ---------------- logits: al[n][H] = sum_c h[n][c]*a[c] (split per head) ----------------
__global__ __launch_bounds__(256) void logits1(const float* __restrict__ h, const float* __restrict__ as,
                                               const float* __restrict__ ad, float* __restrict__ als,
                                               float* __restrict__ ald, int n) {
  int node = blockIdx.x * 4 + (threadIdx.x >> 6);
  int lane = threadIdx.x & 63;
  if (node >= n) return;
  float4 v = *(const float4*)&h[(size_t)node * 256 + lane * 4];
  float4 cs = *(const float4*)&as[lane * 4];  // flat [8][32]: index == column
  float4 cd = *(const float4*)&ad[lane * 4];
  float ps = v.x * cs.x + v.y * cs.y + v.z * cs.z + v.w * cs.w;
  float pd = v.x * cd.x + v.y * cd.y + v.z * cd.z + v.w * cd.w;
#pragma unroll
  for (int o = 1; o < 8; o <<= 1) {  // reduce 8 lanes = 32 cols = one head
    ps += __shfl_xor(ps, o);
    pd += __shfl_xor(pd, o);
  }
  if ((lane & 7) == 0) {
    int head = lane >> 3;
    als[node * 8 + head] = ps;
    ald[node * 8 + head] = pd;
  }
}

__global__ __launch_bounds__(256) void logits2(const float* __restrict__ h, const float* __restrict__ as,
                                               const float* __restrict__ ad, float* __restrict__ als,
                                               float* __restrict__ ald, int n) {
  int node = blockIdx.x * 4 + (threadIdx.x >> 6);
  int lane = threadIdx.x & 63;
  if (node >= n) return;
  float v = h[(size_t)node * 64 + lane];
  float ps = v * as[lane];
  float pd = v * ad[lane];
#pragma unroll
  for (int o = 1; o < 64; o <<= 1) {
    ps += __shfl_xor(ps, o);
    pd += __shfl_xor(pd, o);
  }
  if (lane == 0) {
    als[node] = ps;
    ald[node] = pd;
  }
}

// ---------------- Layer 1 aggregation: one block (256 thr) per dst node ----------------
// 2-way pipelined edge loop: both edges' {csr, al_src, h} loads issue before
// either FMA chain consumes them — halves the dependent-latency depth.
__global__ __launch_bounds__(256) void agg1(const float* __restrict__ h, const float* __restrict__ al_src,
                                            const float* __restrict__ al_dst, const int* __restrict__ off,
                                            const int* __restrict__ csr, const float* __restrict__ bias,
                                            float* __restrict__ outp, int n) {
  int d = blockIdx.x;
  int tid = threadIdx.x;
  int head = tid >> 5;
  float ad = al_dst[d * 8 + head];
  // self loop
  float w0 = expf(lrelu(al_src[d * 8 + head] + ad));
  float acc = w0 * h[(size_t)d * 256 + tid];
  float wsum = w0;
  int beg = off[d], end = off[d + 1];
  int i = beg;
  for (; i + 1 < end; i += 2) {
    int s0 = csr[i], s1 = csr[i + 1];
    float a0 = al_src[s0 * 8 + head];
    float a1 = al_src[s1 * 8 + head];
    float h0 = h[(size_t)s0 * 256 + tid];
    float h1 = h[(size_t)s1 * 256 + tid];
    float wa = expf(lrelu(a0 + ad));
    float wb = expf(lrelu(a1 + ad));
    acc = fmaf(wa, h0, acc);
    acc = fmaf(wb, h1, acc);
    wsum += wa + wb;
  }
  if (i < end) {
    int s = csr[i];
    float w = expf(lrelu(al_src[s * 8 + head] + ad));
    acc = fmaf(w, h[(size_t)s * 256 + tid], acc);
    wsum += w;
  }
  float v = acc / (wsum + 1e-16f) + bias[tid];
  outp[(size_t)d * 256 + tid] = v > 0.f ? v : expm1f(v);  // ELU fused
}

// ---------------- Layer 2 aggregation: one wave per dst node, 4 nodes/block ----------------
__global__ __launch_bounds__(256) void agg2(const float* __restrict__ h, const float* __restrict__ al_src,
                                            const float* __restrict__ al_dst, const int* __restrict__ off,
                                            const int* __restrict__ csr, const float* __restrict__ bias,
                                            float* __restrict__ outp, int n) {
  int d = blockIdx.x * 4 + (threadIdx.x >> 6);
  int c = threadIdx.x & 63;
  if (d >= n) return;
  float ad = al_dst[d];
  float w0 = expf(lrelu(al_src[d] + ad));
  float acc = w0 * h[(size_t)d * 64 + c];
  float wsum = w0;
  int beg = off[d], end = off[d + 1];
  int i = beg;
  for (; i + 1 < end; i += 2) {
    int s0 = csr[i], s1 = csr[i + 1];
    float a0 = al_src[s0];
    float a1 = al_src[s1];
    float h0 = h[(size_t)s0 * 64 + c];
    float h1 = h[(size_t)s1 * 64 + c];
    float wa = expf(lrelu(a0 + ad));
    float wb = expf(lrelu(a1 + ad));
    acc = fmaf(wa, h0, acc);
    acc = fmaf(wb, h1, acc);
    wsum += wa + wb;
  }
  if (i < end) {
    int s = csr[i];
    float w = expf(lrelu(al_src[s] + ad));
    acc = fmaf(w, h[(size_t)s * 64 + c], acc);
    wsum += w;
  }
  outp[(size_t)d * 64 + c] = acc / (wsum + 1e-16f) + bias[c];  // heads=1 -> mean is identity
}

extern "C" void kernel_launch(void* const* d_in, const int* in_sizes, int n_in,
                              void* d_out, int out_size, void* d_ws, size_t ws_size,
                              hipStream_t stream) {
  const float* x  = (const float*)d_in[0];
  const int* ei   = (const int*)d_in[1];
  const float* W1 = (const float*)d_in[2];
  const float* a1s = (const float*)d_in[3];
  const float* a1d = (const float*)d_in[4];
  const float* b1  = (const float*)d_in[5];
  const float* W2  = (const float*)d_in[6];
  const float* a2s = (const float*)d_in[7];
  const float* a2d = (const float*)d_in[8];
  const float* b2  = (const float*)d_in[9];
  float* outp = (float*)d_out;

  int n = in_sizes[0] / 128;   // 50000
  int E = in_sizes[1] / 2;     // 640000
  const int* srcv = ei;
  const int* dstv = ei + E;

  char* wsb = (char*)d_ws;
  size_t p = 0;
  auto alloc = [&](size_t bytes) -> char* {
    char* r = wsb + p;
    p += (bytes + 511) & ~size_t(511);
    return r;
  };
  int* deg  = (int*)alloc((size_t)n * 4);
  int* off  = (int*)alloc(((size_t)n + 1) * 4);
  int* cur  = (int*)alloc((size_t)n * 4);
  int* bsum = (int*)alloc(1024);
  int* csr  = (int*)alloc((size_t)E * 4);
  float* h1   = (float*)alloc((size_t)n * 256 * 4);
  float* al1s = (float*)alloc((size_t)n * 8 * 4);
  float* al1d = (float*)alloc((size_t)n * 8 * 4);
  float* o1   = (float*)alloc((size_t)n * 256 * 4);
  float* h2   = (float*)alloc((size_t)n * 64 * 4);
  float* al2s = (float*)alloc((size_t)n * 4);
  float* al2d = (float*)alloc((size_t)n * 4);
  (void)ws_size;

  hipMemsetAsync(deg, 0, (size_t)n * 4, stream);
  int eb = (E + 255) / 256;
  int nb = (n + 255) / 256;
  count_deg<<<eb, 256, 0, stream>>>(dstv, deg, E);
  scan_partial<<<nb, 256, 0, stream>>>(deg, off, bsum, n);
  scan_bsum<<<1, 256, 0, stream>>>(bsum, off, nb);
  add_carry<<<nb, 256, 0, stream>>>(deg, off, bsum, cur, n);
  fill_csr<<<eb, 256, 0, stream>>>(srcv, dstv, cur, csr, E);

  gemm1<<<(n + 63) / 64, 256, 0, stream>>>(x, W1, h1, n);
  logits1<<<(n + 3) / 4, 256, 0, stream>>>(h1, a1s, a1d, al1s, al1d, n);
  agg1<<<n, 256, 0, stream>>>(h1, al1s, al1d, off, csr, b1, o1, n);
  gemm2<<<(n + 127) / 128, 256, 0, stream>>>(o1, W2, h2, n);
  logits2<<<(n + 3) / 4, 256, 0, stream>>>(h2, a2s, a2d, al2s, al2d, n);
  agg2<<<(n + 3) / 4, 256, 0, stream>>>(h2, al2s, al2d, off, csr, b2, outp, n);
}

// Round 9
// 436.765 us; speedup vs baseline: 1.6442x; 1.0190x over previous
//
#include <hip/hip_runtime.h>

// GAT 2-layer forward for MI355X.
//  - CSR build (histogram + scan + fill), once per call; fill also records dst-per-slot.
//  - Register-tiled f32 GEMMs (8x8 / 8x4 per thread, k-chunk 32, ~VALU-bound).
//  - Edge-parallel alpha kernels: exp(lrelu(logit_src+logit_dst)) computed ONCE
//    per edge×head (was 32x redundant inside agg1 -> VALUBusy 95%).
//  - Gather-aggregate per dst node: wave-per-node, float4 per lane, 2-way
//    pipelined edge loop; softmax normalization folded to a final divide
//    (max-subtraction omitted: shift-invariant, logits bounded ~|8|).

static __device__ __forceinline__ float lrelu(float x) { return x > 0.f ? x : 0.2f * x; }

// ---------------- CSR build ----------------
__global__ void count_deg(const int* __restrict__ dstv, int* __restrict__ deg, int E) {
  int e = blockIdx.x * blockDim.x + threadIdx.x;
  if (e < E) atomicAdd(&deg[dstv[e]], 1);
}

__global__ void scan_partial(const int* __restrict__ deg, int* __restrict__ off,
                             int* __restrict__ bsum, int n) {
  int tid = threadIdx.x;
  int i = blockIdx.x * 256 + tid;
  int v = (i < n) ? deg[i] : 0;
  int lane = tid & 63, w = tid >> 6;
  int sv = v;
#pragma unroll
  for (int o = 1; o < 64; o <<= 1) {
    int t = __shfl_up(sv, o);
    if (lane >= o) sv += t;
  }
  __shared__ int ws[4];
  if (lane == 63) ws[w] = sv;
  __syncthreads();
  int add = 0;
  for (int j = 0; j < w; ++j) add += ws[j];
  sv += add;
  if (i < n) off[i + 1] = sv;
  if (tid == 255) bsum[blockIdx.x] = sv;
}

__global__ void scan_bsum(int* __restrict__ bsum, int* __restrict__ off, int nb) {
  int tid = threadIdx.x;  // 256 threads; requires nb <= 256 (N=50000 -> nb=196)
  int v = (tid < nb) ? bsum[tid] : 0;
  int lane = tid & 63, w = tid >> 6;
  int sv = v;
#pragma unroll
  for (int o = 1; o < 64; o <<= 1) {
    int t = __shfl_up(sv, o);
    if (lane >= o) sv += t;
  }
  __shared__ int ws[4];
  if (lane == 63) ws[w] = sv;
  __syncthreads();
  int add = 0;
  for (int j = 0; j < w; ++j) add += ws[j];
  sv += add;
  if (tid < nb) bsum[tid] = sv - v;  // exclusive prefix of block sums
  if (tid == 0) off[0] = 0;
}

__global__ void add_carry(const int* __restrict__ deg, int* __restrict__ off,
                          const int* __restrict__ bsum, int* __restrict__ cur, int n) {
  int i = blockIdx.x * 256 + threadIdx.x;
  if (i < n) {
    int o = off[i + 1] + bsum[blockIdx.x];
    off[i + 1] = o;
    cur[i] = o - deg[i];  // = off[i]
  }
}

__global__ void fill_csr(const int* __restrict__ srcv, const int* __restrict__ dstv,
                         int* __restrict__ cur, int* __restrict__ csr,
                         int* __restrict__ csr_dst, int E) {
  int e = blockIdx.x * blockDim.x + threadIdx.x;
  if (e < E) {
    int d = dstv[e];
    int p = atomicAdd(&cur[d], 1);
    csr[p] = srcv[e];
    csr_dst[p] = d;
  }
}

// ---------------- GEMM1: [n,128] x [128,256] -> h1, tile 64x256, thread 8x8 ----------------
__global__ __launch_bounds__(256) void gemm1(const float* __restrict__ x, const float* __restrict__ W,
                                             float* __restrict__ h, int n) {
  __shared__ float xs[32][64];   // transposed: xs[k][row]; read=broadcast b128, write bank=row (free)
  __shared__ float Ws[32][256];  // Ws[k][col]; read b32 one-lane-per-bank (free)
  int tid = threadIdx.x;
  int tc = tid & 31;        // owns cols tc + 32*j, j=0..7 (one col per head)
  int tr = tid >> 5;        // owns rows r0 + tr*8 .. +7
  int lr = tid & 63, lj = tid >> 6;  // x-stage coords
  int r0 = blockIdx.x * 64;

  float acc[8][8];
#pragma unroll
  for (int r = 0; r < 8; ++r)
#pragma unroll
    for (int j = 0; j < 8; ++j) acc[r][j] = 0.f;

  for (int k0 = 0; k0 < 128; k0 += 32) {
    __syncthreads();
    // stage x chunk: 64 rows x 32 k
    {
      int rr = r0 + lr;
      float4 v0 = {0, 0, 0, 0}, v1 = {0, 0, 0, 0};
      if (rr < n) {
        const float* p = x + (size_t)rr * 128 + k0 + lj * 8;
        v0 = *(const float4*)p;
        v1 = *(const float4*)(p + 4);
      }
      int kk = lj * 8;
      xs[kk + 0][lr] = v0.x; xs[kk + 1][lr] = v0.y; xs[kk + 2][lr] = v0.z; xs[kk + 3][lr] = v0.w;
      xs[kk + 4][lr] = v1.x; xs[kk + 5][lr] = v1.y; xs[kk + 6][lr] = v1.z; xs[kk + 7][lr] = v1.w;
    }
    // stage W chunk: 32 x 256 floats, flat float4 copy
    {
      const float4* src = (const float4*)(W + (size_t)k0 * 256);
      float4* dst = (float4*)&Ws[0][0];
#pragma unroll
      for (int i = tid; i < 2048; i += 256) dst[i] = src[i];
    }
    __syncthreads();
#pragma unroll 4
    for (int k = 0; k < 32; ++k) {
      float xv[8];
      *(float4*)&xv[0] = *(const float4*)&xs[k][tr * 8];
      *(float4*)&xv[4] = *(const float4*)&xs[k][tr * 8 + 4];
      float wv[8];
#pragma unroll
      for (int j = 0; j < 8; ++j) wv[j] = Ws[k][tc + 32 * j];
#pragma unroll
      for (int r = 0; r < 8; ++r)
#pragma unroll
        for (int j = 0; j < 8; ++j) acc[r][j] = fmaf(xv[r], wv[j], acc[r][j]);
    }
  }
#pragma unroll
  for (int r = 0; r < 8; ++r) {
    int row = r0 + tr * 8 + r;
    if (row < n) {
#pragma unroll
      for (int j = 0; j < 8; ++j) h[(size_t)row * 256 + tc + 32 * j] = acc[r][j];
    }
  }
}

// ---------------- GEMM2: [n,256] x [256,64] -> h2, tile 128x64, thread 8x4 ----------------
__global__ __launch_bounds__(256) void gemm2(const float* __restrict__ xin, const float* __restrict__ W,
                                             float* __restrict__ h, int n) {
  __shared__ float xs[32][128];  // transposed
  __shared__ float Ws[32][64];
  int tid = threadIdx.x;
  int tc = tid & 15;  // owns cols tc + 16*j, j=0..3
  int tr = tid >> 4;  // owns rows r0 + tr*8 .. +7 (tr 0..15 -> 128 rows)
  int r0 = blockIdx.x * 128;

  float acc[8][4];
#pragma unroll
  for (int r = 0; r < 8; ++r)
#pragma unroll
    for (int j = 0; j < 4; ++j) acc[r][j] = 0.f;

  for (int k0 = 0; k0 < 256; k0 += 32) {
    __syncthreads();
    // stage x chunk: 128 rows x 32 k  (1024 float4s)
#pragma unroll
    for (int idx = tid; idx < 1024; idx += 256) {
      int r = idx & 127, q = idx >> 7;
      int rr = r0 + r;
      float4 v = {0, 0, 0, 0};
      if (rr < n) v = *(const float4*)(xin + (size_t)rr * 256 + k0 + q * 4);
      int kk = q * 4;
      xs[kk + 0][r] = v.x; xs[kk + 1][r] = v.y; xs[kk + 2][r] = v.z; xs[kk + 3][r] = v.w;
    }
    // stage W chunk: 32 x 64 floats (512 float4s)
    {
      const float4* src = (const float4*)(W + (size_t)k0 * 64);
      float4* dst = (float4*)&Ws[0][0];
#pragma unroll
      for (int i = tid; i < 512; i += 256) dst[i] = src[i];
    }
    __syncthreads();
#pragma unroll 4
    for (int k = 0; k < 32; ++k) {
      float xv[8];
      *(float4*)&xv[0] = *(const float4*)&xs[k][tr * 8];
      *(float4*)&xv[4] = *(const float4*)&xs[k][tr * 8 + 4];
      float wv[4];
#pragma unroll
      for (int j = 0; j < 4; ++j) wv[j] = Ws[k][tc + 16 * j];
#pragma unroll
      for (int r = 0; r < 8; ++r)
#pragma unroll
        for (int j = 0; j < 4; ++j) acc[r][j] = fmaf(xv[r], wv[j], acc[r][j]);
    }
  }
#pragma unroll
  for (int r = 0; r < 8; ++r) {
    int row = r0 + tr * 8 + r;
    if (row < n) {
#pragma unroll
      for (int j = 0; j < 4; ++j) h[(size_t)row * 64 + tc + 16 * j] = acc[r][j];
    }
  }
}

// ---------------- logits: al[n][H] = sum_c h[n][c]*a[c] (split per head) ----------------
__global__ __launch_bounds__(256) void logits1(const float* __restrict__ h, const float* __restrict__ as,
                                               const float* __restrict__ ad, float* __restrict__ als,
                                               float* __restrict__ ald, int n) {
  int node = blockIdx.x * 4 + (threadIdx.x >> 6);
  int lane = threadIdx.x & 63;
  if (node >= n) return;
  float4 v = *(const float4*)&h[(size_t)node * 256 + lane * 4];
  float4 cs = *(const float4*)&as[lane * 4];  // flat [8][32]: index == column
  float4 cd = *(const float4*)&ad[lane * 4];
  float ps = v.x * cs.x + v.y * cs.y + v.z * cs.z + v.w * cs.w;
  float pd = v.x * cd.x + v.y * cd.y + v.z * cd.z + v.w * cd.w;
#pragma unroll
  for (int o = 1; o < 8; o <<= 1) {  // reduce 8 lanes = 32 cols = one head
    ps += __shfl_xor(ps, o);
    pd += __shfl_xor(pd, o);
  }
  if ((lane & 7) == 0) {
    int head = lane >> 3;
    als[node * 8 + head] = ps;
    ald[node * 8 + head] = pd;
  }
}

__global__ __launch_bounds__(256) void logits2(const float* __restrict__ h, const float* __restrict__ as,
                                               const float* __restrict__ ad, float* __restrict__ als,
                                               float* __restrict__ ald, int n) {
  int node = blockIdx.x * 4 + (threadIdx.x >> 6);
  int lane = threadIdx.x & 63;
  if (node >= n) return;
  float v = h[(size_t)node * 64 + lane];
  float ps = v * as[lane];
  float pd = v * ad[lane];
#pragma unroll
  for (int o = 1; o < 64; o <<= 1) {
    ps += __shfl_xor(ps, o);
    pd += __shfl_xor(pd, o);
  }
  if (lane == 0) {
    als[node] = ps;
    ald[node] = pd;
  }
}

// ---------------- edge-parallel attention weights (alpha), CSR order ----------------
__global__ __launch_bounds__(256) void alpha1_k(const float* __restrict__ als, const float* __restrict__ ald,
                                                const int* __restrict__ csr, const int* __restrict__ csr_dst,
                                                float* __restrict__ alpha, int E) {
  int idx = blockIdx.x * 256 + threadIdx.x;  // over E*8
  if (idx >= E * 8) return;
  int p = idx >> 3, hd = idx & 7;
  int s = csr[p], d = csr_dst[p];
  alpha[idx] = expf(lrelu(als[s * 8 + hd] + ald[d * 8 + hd]));
}

__global__ __launch_bounds__(256) void alpha2_k(const float* __restrict__ als, const float* __restrict__ ald,
                                                const int* __restrict__ csr, const int* __restrict__ csr_dst,
                                                float* __restrict__ alpha, int E) {
  int p = blockIdx.x * 256 + threadIdx.x;
  if (p >= E) return;
  alpha[p] = expf(lrelu(als[csr[p]] + ald[csr_dst[p]]));
}

// ---------------- Layer 1 aggregation: one wave per dst node, float4/lane ----------------
__global__ __launch_bounds__(256) void agg1(const float* __restrict__ h, const float* __restrict__ alpha,
                                            const float* __restrict__ als, const float* __restrict__ ald,
                                            const int* __restrict__ off, const int* __restrict__ csr,
                                            const float* __restrict__ bias, float* __restrict__ outp, int n) {
  int d = blockIdx.x * 4 + (threadIdx.x >> 6);
  if (d >= n) return;
  int lane = threadIdx.x & 63;
  int head = lane >> 3;  // 8 lanes (32 channels) per head
  // self loop
  float w0 = expf(lrelu(als[d * 8 + head] + ald[d * 8 + head]));
  float4 hv = *(const float4*)&h[(size_t)d * 256 + lane * 4];
  float4 acc;
  acc.x = w0 * hv.x; acc.y = w0 * hv.y; acc.z = w0 * hv.z; acc.w = w0 * hv.w;
  float wsum = w0;
  int beg = off[d], end = off[d + 1];
  int i = beg;
  for (; i + 1 < end; i += 2) {
    int s0 = csr[i], s1 = csr[i + 1];
    float wa = alpha[(size_t)i * 8 + head];
    float wb = alpha[(size_t)(i + 1) * 8 + head];
    float4 h0 = *(const float4*)&h[(size_t)s0 * 256 + lane * 4];
    float4 h1 = *(const float4*)&h[(size_t)s1 * 256 + lane * 4];
    acc.x = fmaf(wa, h0.x, acc.x); acc.y = fmaf(wa, h0.y, acc.y);
    acc.z = fmaf(wa, h0.z, acc.z); acc.w = fmaf(wa, h0.w, acc.w);
    acc.x = fmaf(wb, h1.x, acc.x); acc.y = fmaf(wb, h1.y, acc.y);
    acc.z = fmaf(wb, h1.z, acc.z); acc.w = fmaf(wb, h1.w, acc.w);
    wsum += wa + wb;
  }
  if (i < end) {
    int s = csr[i];
    float w = alpha[(size_t)i * 8 + head];
    float4 h0 = *(const float4*)&h[(size_t)s * 256 + lane * 4];
    acc.x = fmaf(w, h0.x, acc.x); acc.y = fmaf(w, h0.y, acc.y);
    acc.z = fmaf(w, h0.z, acc.z); acc.w = fmaf(w, h0.w, acc.w);
    wsum += w;
  }
  float inv = 1.f / (wsum + 1e-16f);
  float4 b = *(const float4*)&bias[lane * 4];
  float4 o;
  o.x = acc.x * inv + b.x; o.y = acc.y * inv + b.y;
  o.z = acc.z * inv + b.z; o.w = acc.w * inv + b.w;
  o.x = o.x > 0.f ? o.x : expm1f(o.x);  // ELU fused
  o.y = o.y > 0.f ? o.y : expm1f(o.y);
  o.z = o.z > 0.f ? o.z : expm1f(o.z);
  o.w = o.w > 0.f ? o.w : expm1f(o.w);
  *(float4*)&outp[(size_t)d * 256 + lane * 4] = o;
}

// ---------------- Layer 2 aggregation: one wave per dst node, 1 float/lane ----------------
__global__ __launch_bounds__(256) void agg2(const float* __restrict__ h, const float* __restrict__ alpha,
                                            const float* __restrict__ als, const float* __restrict__ ald,
                                            const int* __restrict__ off, const int* __restrict__ csr,
                                            const float* __restrict__ bias, float* __restrict__ outp, int n) {
  int d = blockIdx.x * 4 + (threadIdx.x >> 6);
  if (d >= n) return;
  int c = threadIdx.x & 63;
  float w0 = expf(lrelu(als[d] + ald[d]));
  float acc = w0 * h[(size_t)d * 64 + c];
  float wsum = w0;
  int beg = off[d], end = off[d + 1];
  int i = beg;
  for (; i + 1 < end; i += 2) {
    int s0 = csr[i], s1 = csr[i + 1];
    float wa = alpha[i];
    float wb = alpha[i + 1];
    float h0 = h[(size_t)s0 * 64 + c];
    float h1 = h[(size_t)s1 * 64 + c];
    acc = fmaf(wa, h0, acc);
    acc = fmaf(wb, h1, acc);
    wsum += wa + wb;
  }
  if (i < end) {
    int s = csr[i];
    float w = alpha[i];
    acc = fmaf(w, h[(size_t)s * 64 + c], acc);
    wsum += w;
  }
  outp[(size_t)d * 64 + c] = acc / (wsum + 1e-16f) + bias[c];  // heads=1 -> mean is identity
}

extern "C" void kernel_launch(void* const* d_in, const int* in_sizes, int n_in,
                              void* d_out, int out_size, void* d_ws, size_t ws_size,
                              hipStream_t stream) {
  const float* x  = (const float*)d_in[0];
  const int* ei   = (const int*)d_in[1];
  const float* W1 = (const float*)d_in[2];
  const float* a1s = (const float*)d_in[3];
  const float* a1d = (const float*)d_in[4];
  const float* b1  = (const float*)d_in[5];
  const float* W2  = (const float*)d_in[6];
  const float* a2s = (const float*)d_in[7];
  const float* a2d = (const float*)d_in[8];
  const float* b2  = (const float*)d_in[9];
  float* outp = (float*)d_out;

  int n = in_sizes[0] / 128;   // 50000
  int E = in_sizes[1] / 2;     // 640000
  const int* srcv = ei;
  const int* dstv = ei + E;

  char* wsb = (char*)d_ws;
  size_t p = 0;
  auto alloc = [&](size_t bytes) -> char* {
    char* r = wsb + p;
    p += (bytes + 511) & ~size_t(511);
    return r;
  };
  int* deg  = (int*)alloc((size_t)n * 4);
  int* off  = (int*)alloc(((size_t)n + 1) * 4);
  int* cur  = (int*)alloc((size_t)n * 4);
  int* bsum = (int*)alloc(1024);
  int* csr  = (int*)alloc((size_t)E * 4);
  int* csrd = (int*)alloc((size_t)E * 4);
  float* h1   = (float*)alloc((size_t)n * 256 * 4);
  float* al1s = (float*)alloc((size_t)n * 8 * 4);
  float* al1d = (float*)alloc((size_t)n * 8 * 4);
  float* o1   = (float*)alloc((size_t)n * 256 * 4);
  float* h2   = (float*)alloc((size_t)n * 64 * 4);
  float* al2s = (float*)alloc((size_t)n * 4);
  float* al2d = (float*)alloc((size_t)n * 4);
  float* alp1 = (float*)alloc((size_t)E * 8 * 4);
  float* alp2 = (float*)alloc((size_t)E * 4);
  (void)ws_size;

  hipMemsetAsync(deg, 0, (size_t)n * 4, stream);
  int eb = (E + 255) / 256;
  int nb = (n + 255) / 256;
  count_deg<<<eb, 256, 0, stream>>>(dstv, deg, E);
  scan_partial<<<nb, 256, 0, stream>>>(deg, off, bsum, n);
  scan_bsum<<<1, 256, 0, stream>>>(bsum, off, nb);
  add_carry<<<nb, 256, 0, stream>>>(deg, off, bsum, cur, n);
  fill_csr<<<eb, 256, 0, stream>>>(srcv, dstv, cur, csr, csrd, E);

  gemm1<<<(n + 63) / 64, 256, 0, stream>>>(x, W1, h1, n);
  logits1<<<(n + 3) / 4, 256, 0, stream>>>(h1, a1s, a1d, al1s, al1d, n);
  alpha1_k<<<(E * 8 + 255) / 256, 256, 0, stream>>>(al1s, al1d, csr, csrd, alp1, E);
  agg1<<<(n + 3) / 4, 256, 0, stream>>>(h1, alp1, al1s, al1d, off, csr, b1, o1, n);
  gemm2<<<(n + 127) / 128, 256, 0, stream>>>(o1, W2, h2, n);
  logits2<<<(n + 3) / 4, 256, 0, stream>>>(h2, a2s, a2d, al2s, al2d, n);
  alpha2_k<<<eb, 256, 0, stream>>>(al2s, al2d, csr, csrd, alp2, E);
  agg2<<<(n + 3) / 4, 256, 0, stream>>>(h2, alp2, al2s, al2d, off, csr, b2, outp, n);
}

// Round 10
// 410.485 us; speedup vs baseline: 1.7495x; 1.0640x over previous
//
#include <hip/hip_runtime.h>

// GAT 2-layer forward for MI355X.
//  - CSR build (histogram + scan + fill), once per call.
//  - Register-tiled f32 GEMMs (8x8 / 8x4 per thread, k-chunk 32).
//  - Aggregation: wave-per-node gather with attention weights computed inline
//    wave-parallel (8-lane redundant exp, VALU was 76% idle) and 4-way
//    pipelined edge loop (latency-bound: VALU 24%, HBM 48% at 2-way).
//    Softmax normalization folded to a final divide (max-subtraction omitted:
//    shift-invariant, logits bounded ~|8|).

static __device__ __forceinline__ float lrelu(float x) { return x > 0.f ? x : 0.2f * x; }

// ---------------- CSR build ----------------
__global__ void count_deg(const int* __restrict__ dstv, int* __restrict__ deg, int E) {
  int e = blockIdx.x * blockDim.x + threadIdx.x;
  if (e < E) atomicAdd(&deg[dstv[e]], 1);
}

__global__ void scan_partial(const int* __restrict__ deg, int* __restrict__ off,
                             int* __restrict__ bsum, int n) {
  int tid = threadIdx.x;
  int i = blockIdx.x * 256 + tid;
  int v = (i < n) ? deg[i] : 0;
  int lane = tid & 63, w = tid >> 6;
  int sv = v;
#pragma unroll
  for (int o = 1; o < 64; o <<= 1) {
    int t = __shfl_up(sv, o);
    if (lane >= o) sv += t;
  }
  __shared__ int ws[4];
  if (lane == 63) ws[w] = sv;
  __syncthreads();
  int add = 0;
  for (int j = 0; j < w; ++j) add += ws[j];
  sv += add;
  if (i < n) off[i + 1] = sv;
  if (tid == 255) bsum[blockIdx.x] = sv;
}

__global__ void scan_bsum(int* __restrict__ bsum, int* __restrict__ off, int nb) {
  int tid = threadIdx.x;  // 256 threads; requires nb <= 256 (N=50000 -> nb=196)
  int v = (tid < nb) ? bsum[tid] : 0;
  int lane = tid & 63, w = tid >> 6;
  int sv = v;
#pragma unroll
  for (int o = 1; o < 64; o <<= 1) {
    int t = __shfl_up(sv, o);
    if (lane >= o) sv += t;
  }
  __shared__ int ws[4];
  if (lane == 63) ws[w] = sv;
  __syncthreads();
  int add = 0;
  for (int j = 0; j < w; ++j) add += ws[j];
  sv += add;
  if (tid < nb) bsum[tid] = sv - v;  // exclusive prefix of block sums
  if (tid == 0) off[0] = 0;
}

__global__ void add_carry(const int* __restrict__ deg, int* __restrict__ off,
                          const int* __restrict__ bsum, int* __restrict__ cur, int n) {
  int i = blockIdx.x * 256 + threadIdx.x;
  if (i < n) {
    int o = off[i + 1] + bsum[blockIdx.x];
    off[i + 1] = o;
    cur[i] = o - deg[i];  // = off[i]
  }
}

__global__ void fill_csr(const int* __restrict__ srcv, const int* __restrict__ dstv,
                         int* __restrict__ cur, int* __restrict__ csr, int E) {
  int e = blockIdx.x * blockDim.x + threadIdx.x;
  if (e < E) {
    int p = atomicAdd(&cur[dstv[e]], 1);
    csr[p] = srcv[e];
  }
}

// ---------------- GEMM1: [n,128] x [128,256] -> h1, tile 64x256, thread 8x8 ----------------
__global__ __launch_bounds__(256) void gemm1(const float* __restrict__ x, const float* __restrict__ W,
                                             float* __restrict__ h, int n) {
  __shared__ float xs[32][64];   // transposed: xs[k][row]; read=broadcast b128, write bank=row (free)
  __shared__ float Ws[32][256];  // Ws[k][col]; read b32 one-lane-per-bank (free)
  int tid = threadIdx.x;
  int tc = tid & 31;        // owns cols tc + 32*j, j=0..7 (one col per head)
  int tr = tid >> 5;        // owns rows r0 + tr*8 .. +7
  int lr = tid & 63, lj = tid >> 6;  // x-stage coords
  int r0 = blockIdx.x * 64;

  float acc[8][8];
#pragma unroll
  for (int r = 0; r < 8; ++r)
#pragma unroll
    for (int j = 0; j < 8; ++j) acc[r][j] = 0.f;

  for (int k0 = 0; k0 < 128; k0 += 32) {
    __syncthreads();
    // stage x chunk: 64 rows x 32 k
    {
      int rr = r0 + lr;
      float4 v0 = {0, 0, 0, 0}, v1 = {0, 0, 0, 0};
      if (rr < n) {
        const float* p = x + (size_t)rr * 128 + k0 + lj * 8;
        v0 = *(const float4*)p;
        v1 = *(const float4*)(p + 4);
      }
      int kk = lj * 8;
      xs[kk + 0][lr] = v0.x; xs[kk + 1][lr] = v0.y; xs[kk + 2][lr] = v0.z; xs[kk + 3][lr] = v0.w;
      xs[kk + 4][lr] = v1.x; xs[kk + 5][lr] = v1.y; xs[kk + 6][lr] = v1.z; xs[kk + 7][lr] = v1.w;
    }
    // stage W chunk: 32 x 256 floats, flat float4 copy
    {
      const float4* src = (const float4*)(W + (size_t)k0 * 256);
      float4* dst = (float4*)&Ws[0][0];
#pragma unroll
      for (int i = tid; i < 2048; i += 256) dst[i] = src[i];
    }
    __syncthreads();
#pragma unroll 4
    for (int k = 0; k < 32; ++k) {
      float xv[8];
      *(float4*)&xv[0] = *(const float4*)&xs[k][tr * 8];
      *(float4*)&xv[4] = *(const float4*)&xs[k][tr * 8 + 4];
      float wv[8];
#pragma unroll
      for (int j = 0; j < 8; ++j) wv[j] = Ws[k][tc + 32 * j];
#pragma unroll
      for (int r = 0; r < 8; ++r)
#pragma unroll
        for (int j = 0; j < 8; ++j) acc[r][j] = fmaf(xv[r], wv[j], acc[r][j]);
    }
  }
#pragma unroll
  for (int r = 0; r < 8; ++r) {
    int row = r0 + tr * 8 + r;
    if (row < n) {
#pragma unroll
      for (int j = 0; j < 8; ++j) h[(size_t)row * 256 + tc + 32 * j] = acc[r][j];
    }
  }
}

// ---------------- GEMM2: [n,256] x [256,64] -> h2, tile 128x64, thread 8x4 ----------------
__global__ __launch_bounds__(256) void gemm2(const float* __restrict__ xin, const float* __restrict__ W,
                                             float* __restrict__ h, int n) {
  __shared__ float xs[32][128];  // transposed
  __shared__ float Ws[32][64];
  int tid = threadIdx.x;
  int tc = tid & 15;  // owns cols tc + 16*j, j=0..3
  int tr = tid >> 4;  // owns rows r0 + tr*8 .. +7 (tr 0..15 -> 128 rows)
  int r0 = blockIdx.x * 128;

  float acc[8][4];
#pragma unroll
  for (int r = 0; r < 8; ++r)
#pragma unroll
    for (int j = 0; j < 4; ++j) acc[r][j] = 0.f;

  for (int k0 = 0; k0 < 256; k0 += 32) {
    __syncthreads();
    // stage x chunk: 128 rows x 32 k  (1024 float4s)
#pragma unroll
    for (int idx = tid; idx < 1024; idx += 256) {
      int r = idx & 127, q = idx >> 7;
      int rr = r0 + r;
      float4 v = {0, 0, 0, 0};
      if (rr < n) v = *(const float4*)(xin + (size_t)rr * 256 + k0 + q * 4);
      int kk = q * 4;
      xs[kk + 0][r] = v.x; xs[kk + 1][r] = v.y; xs[kk + 2][r] = v.z; xs[kk + 3][r] = v.w;
    }
    // stage W chunk: 32 x 64 floats (512 float4s)
    {
      const float4* src = (const float4*)(W + (size_t)k0 * 64);
      float4* dst = (float4*)&Ws[0][0];
#pragma unroll
      for (int i = tid; i < 512; i += 256) dst[i] = src[i];
    }
    __syncthreads();
#pragma unroll 4
    for (int k = 0; k < 32; ++k) {
      float xv[8];
      *(float4*)&xv[0] = *(const float4*)&xs[k][tr * 8];
      *(float4*)&xv[4] = *(const float4*)&xs[k][tr * 8 + 4];
      float wv[4];
#pragma unroll
      for (int j = 0; j < 4; ++j) wv[j] = Ws[k][tc + 16 * j];
#pragma unroll
      for (int r = 0; r < 8; ++r)
#pragma unroll
        for (int j = 0; j < 4; ++j) acc[r][j] = fmaf(xv[r], wv[j], acc[r][j]);
    }
  }
#pragma unroll
  for (int r = 0; r < 8; ++r) {
    int row = r0 + tr * 8 + r;
    if (row < n) {
#pragma unroll
      for (int j = 0; j < 4; ++j) h[(size_t)row * 64 + tc + 16 * j] = acc[r][j];
    }
  }
}

// ---------------- logits: al[n][H] = sum_c h[n][c]*a[c] (split per head) ----------------
__global__ __launch_bounds__(256) void logits1(const float* __restrict__ h, const float* __restrict__ as,
                                               const float* __restrict__ ad, float* __restrict__ als,
                                               float* __restrict__ ald, int n) {
  int node = blockIdx.x * 4 + (threadIdx.x >> 6);
  int lane = threadIdx.x & 63;
  if (node >= n) return;
  float4 v = *(const float4*)&h[(size_t)node * 256 + lane * 4];
  float4 cs = *(const float4*)&as[lane * 4];  // flat [8][32]: index == column
  float4 cd = *(const float4*)&ad[lane * 4];
  float ps = v.x * cs.x + v.y * cs.y + v.z * cs.z + v.w * cs.w;
  float pd = v.x * cd.x + v.y * cd.y + v.z * cd.z + v.w * cd.w;
#pragma unroll
  for (int o = 1; o < 8; o <<= 1) {  // reduce 8 lanes = 32 cols = one head
    ps += __shfl_xor(ps, o);
    pd += __shfl_xor(pd, o);
  }
  if ((lane & 7) == 0) {
    int head = lane >> 3;
    als[node * 8 + head] = ps;
    ald[node * 8 + head] = pd;
  }
}

__global__ __launch_bounds__(256) void logits2(const float* __restrict__ h, const float* __restrict__ as,
                                               const float* __restrict__ ad, float* __restrict__ als,
                                               float* __restrict__ ald, int n) {
  int node = blockIdx.x * 4 + (threadIdx.x >> 6);
  int lane = threadIdx.x & 63;
  if (node >= n) return;
  float v = h[(size_t)node * 64 + lane];
  float ps = v * as[lane];
  float pd = v * ad[lane];
#pragma unroll
  for (int o = 1; o < 64; o <<= 1) {
    ps += __shfl_xor(ps, o);
    pd += __shfl_xor(pd, o);
  }
  if (lane == 0) {
    als[node] = ps;
    ald[node] = pd;
  }
}

// ---------------- Layer 1 aggregation: one wave per dst node, float4/lane ----------------
// Attention weight computed inline (8-lane group redundant; VALU had 76% headroom).
// 4-way pipelined edge loop for latency hiding.
__global__ __launch_bounds__(256) void agg1(const float* __restrict__ h,
                                            const float* __restrict__ als, const float* __restrict__ ald,
                                            const int* __restrict__ off, const int* __restrict__ csr,
                                            const float* __restrict__ bias, float* __restrict__ outp, int n) {
  int d = blockIdx.x * 4 + (threadIdx.x >> 6);
  if (d >= n) return;
  int lane = threadIdx.x & 63;
  int head = lane >> 3;  // 8 lanes (32 channels) per head
  float ad = ald[d * 8 + head];
  // self loop
  float w0 = expf(lrelu(als[d * 8 + head] + ad));
  float4 hv = *(const float4*)&h[(size_t)d * 256 + lane * 4];
  float4 acc;
  acc.x = w0 * hv.x; acc.y = w0 * hv.y; acc.z = w0 * hv.z; acc.w = w0 * hv.w;
  float wsum = w0;
  int beg = off[d], end = off[d + 1];
  int i = beg;
  for (; i + 3 < end; i += 4) {
    int s0 = csr[i], s1 = csr[i + 1], s2 = csr[i + 2], s3 = csr[i + 3];
    float a0 = als[s0 * 8 + head];
    float a1 = als[s1 * 8 + head];
    float a2 = als[s2 * 8 + head];
    float a3 = als[s3 * 8 + head];
    float4 h0 = *(const float4*)&h[(size_t)s0 * 256 + lane * 4];
    float4 h1 = *(const float4*)&h[(size_t)s1 * 256 + lane * 4];
    float4 h2 = *(const float4*)&h[(size_t)s2 * 256 + lane * 4];
    float4 h3 = *(const float4*)&h[(size_t)s3 * 256 + lane * 4];
    float wa = expf(lrelu(a0 + ad));
    float wb = expf(lrelu(a1 + ad));
    float wc = expf(lrelu(a2 + ad));
    float wd = expf(lrelu(a3 + ad));
    acc.x = fmaf(wa, h0.x, acc.x); acc.y = fmaf(wa, h0.y, acc.y);
    acc.z = fmaf(wa, h0.z, acc.z); acc.w = fmaf(wa, h0.w, acc.w);
    acc.x = fmaf(wb, h1.x, acc.x); acc.y = fmaf(wb, h1.y, acc.y);
    acc.z = fmaf(wb, h1.z, acc.z); acc.w = fmaf(wb, h1.w, acc.w);
    acc.x = fmaf(wc, h2.x, acc.x); acc.y = fmaf(wc, h2.y, acc.y);
    acc.z = fmaf(wc, h2.z, acc.z); acc.w = fmaf(wc, h2.w, acc.w);
    acc.x = fmaf(wd, h3.x, acc.x); acc.y = fmaf(wd, h3.y, acc.y);
    acc.z = fmaf(wd, h3.z, acc.z); acc.w = fmaf(wd, h3.w, acc.w);
    wsum += (wa + wb) + (wc + wd);
  }
  for (; i < end; ++i) {
    int s = csr[i];
    float w = expf(lrelu(als[s * 8 + head] + ad));
    float4 h0 = *(const float4*)&h[(size_t)s * 256 + lane * 4];
    acc.x = fmaf(w, h0.x, acc.x); acc.y = fmaf(w, h0.y, acc.y);
    acc.z = fmaf(w, h0.z, acc.z); acc.w = fmaf(w, h0.w, acc.w);
    wsum += w;
  }
  float inv = 1.f / (wsum + 1e-16f);
  float4 b = *(const float4*)&bias[lane * 4];
  float4 o;
  o.x = acc.x * inv + b.x; o.y = acc.y * inv + b.y;
  o.z = acc.z * inv + b.z; o.w = acc.w * inv + b.w;
  o.x = o.x > 0.f ? o.x : expm1f(o.x);  // ELU fused
  o.y = o.y > 0.f ? o.y : expm1f(o.y);
  o.z = o.z > 0.f ? o.z : expm1f(o.z);
  o.w = o.w > 0.f ? o.w : expm1f(o.w);
  *(float4*)&outp[(size_t)d * 256 + lane * 4] = o;
}

// ---------------- Layer 2 aggregation: one wave per dst node, 1 float/lane ----------------
__global__ __launch_bounds__(256) void agg2(const float* __restrict__ h,
                                            const float* __restrict__ als, const float* __restrict__ ald,
                                            const int* __restrict__ off, const int* __restrict__ csr,
                                            const float* __restrict__ bias, float* __restrict__ outp, int n) {
  int d = blockIdx.x * 4 + (threadIdx.x >> 6);
  if (d >= n) return;
  int c = threadIdx.x & 63;
  float ad = ald[d];
  float w0 = expf(lrelu(als[d] + ad));
  float acc = w0 * h[(size_t)d * 64 + c];
  float wsum = w0;
  int beg = off[d], end = off[d + 1];
  int i = beg;
  for (; i + 3 < end; i += 4) {
    int s0 = csr[i], s1 = csr[i + 1], s2 = csr[i + 2], s3 = csr[i + 3];
    float a0 = als[s0];
    float a1 = als[s1];
    float a2 = als[s2];
    float a3 = als[s3];
    float h0 = h[(size_t)s0 * 64 + c];
    float h1 = h[(size_t)s1 * 64 + c];
    float h2 = h[(size_t)s2 * 64 + c];
    float h3 = h[(size_t)s3 * 64 + c];
    float wa = expf(lrelu(a0 + ad));
    float wb = expf(lrelu(a1 + ad));
    float wc = expf(lrelu(a2 + ad));
    float wd = expf(lrelu(a3 + ad));
    acc = fmaf(wa, h0, acc);
    acc = fmaf(wb, h1, acc);
    acc = fmaf(wc, h2, acc);
    acc = fmaf(wd, h3, acc);
    wsum += (wa + wb) + (wc + wd);
  }
  for (; i < end; ++i) {
    int s = csr[i];
    float w = expf(lrelu(als[s] + ad));
    acc = fmaf(w, h[(size_t)s * 64 + c], acc);
    wsum += w;
  }
  outp[(size_t)d * 64 + c] = acc / (wsum + 1e-16f) + bias[c];  // heads=1 -> mean is identity
}

extern "C" void kernel_launch(void* const* d_in, const int* in_sizes, int n_in,
                              void* d_out, int out_size, void* d_ws, size_t ws_size,
                              hipStream_t stream) {
  const float* x  = (const float*)d_in[0];
  const int* ei   = (const int*)d_in[1];
  const float* W1 = (const float*)d_in[2];
  const float* a1s = (const float*)d_in[3];
  const float* a1d = (const float*)d_in[4];
  const float* b1  = (const float*)d_in[5];
  const float* W2  = (const float*)d_in[6];
  const float* a2s = (const float*)d_in[7];
  const float* a2d = (const float*)d_in[8];
  const float* b2  = (const float*)d_in[9];
  float* outp = (float*)d_out;

  int n = in_sizes[0] / 128;   // 50000
  int E = in_sizes[1] / 2;     // 640000
  const int* srcv = ei;
  const int* dstv = ei + E;

  char* wsb = (char*)d_ws;
  size_t p = 0;
  auto alloc = [&](size_t bytes) -> char* {
    char* r = wsb + p;
    p += (bytes + 511) & ~size_t(511);
    return r;
  };
  int* deg  = (int*)alloc((size_t)n * 4);
  int* off  = (int*)alloc(((size_t)n + 1) * 4);
  int* cur  = (int*)alloc((size_t)n * 4);
  int* bsum = (int*)alloc(1024);
  int* csr  = (int*)alloc((size_t)E * 4);
  float* h1   = (float*)alloc((size_t)n * 256 * 4);
  float* al1s = (float*)alloc((size_t)n * 8 * 4);
  float* al1d = (float*)alloc((size_t)n * 8 * 4);
  float* o1   = (float*)alloc((size_t)n * 256 * 4);
  float* h2   = (float*)alloc((size_t)n * 64 * 4);
  float* al2s = (float*)alloc((size_t)n * 4);
  float* al2d = (float*)alloc((size_t)n * 4);
  (void)ws_size;

  hipMemsetAsync(deg, 0, (size_t)n * 4, stream);
  int eb = (E + 255) / 256;
  int nb = (n + 255) / 256;
  count_deg<<<eb, 256, 0, stream>>>(dstv, deg, E);
  scan_partial<<<nb, 256, 0, stream>>>(deg, off, bsum, n);
  scan_bsum<<<1, 256, 0, stream>>>(bsum, off, nb);
  add_carry<<<nb, 256, 0, stream>>>(deg, off, bsum, cur, n);
  fill_csr<<<eb, 256, 0, stream>>>(srcv, dstv, cur, csr, E);

  gemm1<<<(n + 63) / 64, 256, 0, stream>>>(x, W1, h1, n);
  logits1<<<(n + 3) / 4, 256, 0, stream>>>(h1, a1s, a1d, al1s, al1d, n);
  agg1<<<(n + 3) / 4, 256, 0, stream>>>(h1, al1s, al1d, off, csr, b1, o1, n);
  gemm2<<<(n + 127) / 128, 256, 0, stream>>>(o1, W2, h2, n);
  logits2<<<(n + 3) / 4, 256, 0, stream>>>(h2, a2s, a2d, al2s, al2d, n);
  agg2<<<(n + 3) / 4, 256, 0, stream>>>(h2, al2s, al2d, off, csr, b2, outp, n);
}

// Round 11
// 368.328 us; speedup vs baseline: 1.9497x; 1.1145x over previous
//
#include <hip/hip_runtime.h>
#include <hip/hip_fp16.h>

// GAT 2-layer forward for MI355X.
//  - CSR build (histogram + scan + fill), once per call.
//  - Register-tiled f32 GEMMs (8x8 / 8x4 per thread, k-chunk 32).
//  - agg1 gathers a packed-fp16 copy of h1 (halves the random-gather bytes;
//    gather path measured BW-bound at ~3.8 TB/s for 1KB-row gathers).
//    Attention logits stay f32 (bit-identical alphas). Wave-per-node,
//    inline wave-parallel exp, 4-way pipelined edge loop.
//    Softmax normalization folded to a final divide (max-subtraction omitted:
//    shift-invariant, logits bounded ~|8|).

static __device__ __forceinline__ float lrelu(float x) { return x > 0.f ? x : 0.2f * x; }

struct alignas(8) Half4 { __half2 lo, hi; };

// ---------------- CSR build ----------------
__global__ void count_deg(const int* __restrict__ dstv, int* __restrict__ deg, int E) {
  int e = blockIdx.x * blockDim.x + threadIdx.x;
  if (e < E) atomicAdd(&deg[dstv[e]], 1);
}

__global__ void scan_partial(const int* __restrict__ deg, int* __restrict__ off,
                             int* __restrict__ bsum, int n) {
  int tid = threadIdx.x;
  int i = blockIdx.x * 256 + tid;
  int v = (i < n) ? deg[i] : 0;
  int lane = tid & 63, w = tid >> 6;
  int sv = v;
#pragma unroll
  for (int o = 1; o < 64; o <<= 1) {
    int t = __shfl_up(sv, o);
    if (lane >= o) sv += t;
  }
  __shared__ int ws[4];
  if (lane == 63) ws[w] = sv;
  __syncthreads();
  int add = 0;
  for (int j = 0; j < w; ++j) add += ws[j];
  sv += add;
  if (i < n) off[i + 1] = sv;
  if (tid == 255) bsum[blockIdx.x] = sv;
}

__global__ void scan_bsum(int* __restrict__ bsum, int* __restrict__ off, int nb) {
  int tid = threadIdx.x;  // 256 threads; requires nb <= 256 (N=50000 -> nb=196)
  int v = (tid < nb) ? bsum[tid] : 0;
  int lane = tid & 63, w = tid >> 6;
  int sv = v;
#pragma unroll
  for (int o = 1; o < 64; o <<= 1) {
    int t = __shfl_up(sv, o);
    if (lane >= o) sv += t;
  }
  __shared__ int ws[4];
  if (lane == 63) ws[w] = sv;
  __syncthreads();
  int add = 0;
  for (int j = 0; j < w; ++j) add += ws[j];
  sv += add;
  if (tid < nb) bsum[tid] = sv - v;  // exclusive prefix of block sums
  if (tid == 0) off[0] = 0;
}

__global__ void add_carry(const int* __restrict__ deg, int* __restrict__ off,
                          const int* __restrict__ bsum, int* __restrict__ cur, int n) {
  int i = blockIdx.x * 256 + threadIdx.x;
  if (i < n) {
    int o = off[i + 1] + bsum[blockIdx.x];
    off[i + 1] = o;
    cur[i] = o - deg[i];  // = off[i]
  }
}

__global__ void fill_csr(const int* __restrict__ srcv, const int* __restrict__ dstv,
                         int* __restrict__ cur, int* __restrict__ csr, int E) {
  int e = blockIdx.x * blockDim.x + threadIdx.x;
  if (e < E) {
    int p = atomicAdd(&cur[dstv[e]], 1);
    csr[p] = srcv[e];
  }
}

// ---------------- GEMM1: [n,128] x [128,256] -> h1 (f32) + h1h (fp16) ----------------
__global__ __launch_bounds__(256) void gemm1(const float* __restrict__ x, const float* __restrict__ W,
                                             float* __restrict__ h, __half* __restrict__ hh, int n) {
  __shared__ float xs[32][64];   // transposed: xs[k][row]; read=broadcast b128, write bank=row (free)
  __shared__ float Ws[32][256];  // Ws[k][col]; read b32 one-lane-per-bank (free)
  int tid = threadIdx.x;
  int tc = tid & 31;        // owns cols tc + 32*j, j=0..7 (one col per head)
  int tr = tid >> 5;        // owns rows r0 + tr*8 .. +7
  int lr = tid & 63, lj = tid >> 6;  // x-stage coords
  int r0 = blockIdx.x * 64;

  float acc[8][8];
#pragma unroll
  for (int r = 0; r < 8; ++r)
#pragma unroll
    for (int j = 0; j < 8; ++j) acc[r][j] = 0.f;

  for (int k0 = 0; k0 < 128; k0 += 32) {
    __syncthreads();
    // stage x chunk: 64 rows x 32 k
    {
      int rr = r0 + lr;
      float4 v0 = {0, 0, 0, 0}, v1 = {0, 0, 0, 0};
      if (rr < n) {
        const float* p = x + (size_t)rr * 128 + k0 + lj * 8;
        v0 = *(const float4*)p;
        v1 = *(const float4*)(p + 4);
      }
      int kk = lj * 8;
      xs[kk + 0][lr] = v0.x; xs[kk + 1][lr] = v0.y; xs[kk + 2][lr] = v0.z; xs[kk + 3][lr] = v0.w;
      xs[kk + 4][lr] = v1.x; xs[kk + 5][lr] = v1.y; xs[kk + 6][lr] = v1.z; xs[kk + 7][lr] = v1.w;
    }
    // stage W chunk: 32 x 256 floats, flat float4 copy
    {
      const float4* src = (const float4*)(W + (size_t)k0 * 256);
      float4* dst = (float4*)&Ws[0][0];
#pragma unroll
      for (int i = tid; i < 2048; i += 256) dst[i] = src[i];
    }
    __syncthreads();
#pragma unroll 4
    for (int k = 0; k < 32; ++k) {
      float xv[8];
      *(float4*)&xv[0] = *(const float4*)&xs[k][tr * 8];
      *(float4*)&xv[4] = *(const float4*)&xs[k][tr * 8 + 4];
      float wv[8];
#pragma unroll
      for (int j = 0; j < 8; ++j) wv[j] = Ws[k][tc + 32 * j];
#pragma unroll
      for (int r = 0; r < 8; ++r)
#pragma unroll
        for (int j = 0; j < 8; ++j) acc[r][j] = fmaf(xv[r], wv[j], acc[r][j]);
    }
  }
#pragma unroll
  for (int r = 0; r < 8; ++r) {
    int row = r0 + tr * 8 + r;
    if (row < n) {
#pragma unroll
      for (int j = 0; j < 8; ++j) {
        h[(size_t)row * 256 + tc + 32 * j] = acc[r][j];
        hh[(size_t)row * 256 + tc + 32 * j] = __float2half(acc[r][j]);
      }
    }
  }
}

// ---------------- GEMM2: [n,256] x [256,64] -> h2, tile 128x64, thread 8x4 ----------------
__global__ __launch_bounds__(256) void gemm2(const float* __restrict__ xin, const float* __restrict__ W,
                                             float* __restrict__ h, int n) {
  __shared__ float xs[32][128];  // transposed
  __shared__ float Ws[32][64];
  int tid = threadIdx.x;
  int tc = tid & 15;  // owns cols tc + 16*j, j=0..3
  int tr = tid >> 4;  // owns rows r0 + tr*8 .. +7 (tr 0..15 -> 128 rows)
  int r0 = blockIdx.x * 128;

  float acc[8][4];
#pragma unroll
  for (int r = 0; r < 8; ++r)
#pragma unroll
    for (int j = 0; j < 4; ++j) acc[r][j] = 0.f;

  for (int k0 = 0; k0 < 256; k0 += 32) {
    __syncthreads();
    // stage x chunk: 128 rows x 32 k  (1024 float4s)
#pragma unroll
    for (int idx = tid; idx < 1024; idx += 256) {
      int r = idx & 127, q = idx >> 7;
      int rr = r0 + r;
      float4 v = {0, 0, 0, 0};
      if (rr < n) v = *(const float4*)(xin + (size_t)rr * 256 + k0 + q * 4);
      int kk = q * 4;
      xs[kk + 0][r] = v.x; xs[kk + 1][r] = v.y; xs[kk + 2][r] = v.z; xs[kk + 3][r] = v.w;
    }
    // stage W chunk: 32 x 64 floats (512 float4s)
    {
      const float4* src = (const float4*)(W + (size_t)k0 * 64);
      float4* dst = (float4*)&Ws[0][0];
#pragma unroll
      for (int i = tid; i < 512; i += 256) dst[i] = src[i];
    }
    __syncthreads();
#pragma unroll 4
    for (int k = 0; k < 32; ++k) {
      float xv[8];
      *(float4*)&xv[0] = *(const float4*)&xs[k][tr * 8];
      *(float4*)&xv[4] = *(const float4*)&xs[k][tr * 8 + 4];
      float wv[4];
#pragma unroll
      for (int j = 0; j < 4; ++j) wv[j] = Ws[k][tc + 16 * j];
#pragma unroll
      for (int r = 0; r < 8; ++r)
#pragma unroll
        for (int j = 0; j < 4; ++j) acc[r][j] = fmaf(xv[r], wv[j], acc[r][j]);
    }
  }
#pragma unroll
  for (int r = 0; r < 8; ++r) {
    int row = r0 + tr * 8 + r;
    if (row < n) {
#pragma unroll
      for (int j = 0; j < 4; ++j) h[(size_t)row * 64 + tc + 16 * j] = acc[r][j];
    }
  }
}

// ---------------- logits: al[n][H] = sum_c h[n][c]*a[c] (split per head) ----------------
__global__ __launch_bounds__(256) void logits1(const float* __restrict__ h, const float* __restrict__ as,
                                               const float* __restrict__ ad, float* __restrict__ als,
                                               float* __restrict__ ald, int n) {
  int node = blockIdx.x * 4 + (threadIdx.x >> 6);
  int lane = threadIdx.x & 63;
  if (node >= n) return;
  float4 v = *(const float4*)&h[(size_t)node * 256 + lane * 4];
  float4 cs = *(const float4*)&as[lane * 4];  // flat [8][32]: index == column
  float4 cd = *(const float4*)&ad[lane * 4];
  float ps = v.x * cs.x + v.y * cs.y + v.z * cs.z + v.w * cs.w;
  float pd = v.x * cd.x + v.y * cd.y + v.z * cd.z + v.w * cd.w;
#pragma unroll
  for (int o = 1; o < 8; o <<= 1) {  // reduce 8 lanes = 32 cols = one head
    ps += __shfl_xor(ps, o);
    pd += __shfl_xor(pd, o);
  }
  if ((lane & 7) == 0) {
    int head = lane >> 3;
    als[node * 8 + head] = ps;
    ald[node * 8 + head] = pd;
  }
}

__global__ __launch_bounds__(256) void logits2(const float* __restrict__ h, const float* __restrict__ as,
                                               const float* __restrict__ ad, float* __restrict__ als,
                                               float* __restrict__ ald, int n) {
  int node = blockIdx.x * 4 + (threadIdx.x >> 6);
  int lane = threadIdx.x & 63;
  if (node >= n) return;
  float v = h[(size_t)node * 64 + lane];
  float ps = v * as[lane];
  float pd = v * ad[lane];
#pragma unroll
  for (int o = 1; o < 64; o <<= 1) {
    ps += __shfl_xor(ps, o);
    pd += __shfl_xor(pd, o);
  }
  if (lane == 0) {
    als[node] = ps;
    ald[node] = pd;
  }
}

// ---------------- Layer 1 aggregation: one wave per dst node, fp16x4/lane gather ----------------
__global__ __launch_bounds__(256) void agg1(const __half* __restrict__ hh,
                                            const float* __restrict__ als, const float* __restrict__ ald,
                                            const int* __restrict__ off, const int* __restrict__ csr,
                                            const float* __restrict__ bias, float* __restrict__ outp, int n) {
  int d = blockIdx.x * 4 + (threadIdx.x >> 6);
  if (d >= n) return;
  int lane = threadIdx.x & 63;
  int head = lane >> 3;  // 8 lanes (32 channels) per head
  float ad = ald[d * 8 + head];
  // self loop
  float w0 = expf(lrelu(als[d * 8 + head] + ad));
  Half4 qv = *(const Half4*)&hh[(size_t)d * 256 + lane * 4];
  float2 vlo = __half22float2(qv.lo), vhi = __half22float2(qv.hi);
  float4 acc;
  acc.x = w0 * vlo.x; acc.y = w0 * vlo.y; acc.z = w0 * vhi.x; acc.w = w0 * vhi.y;
  float wsum = w0;
  int beg = off[d], end = off[d + 1];
  int i = beg;
  for (; i + 3 < end; i += 4) {
    int s0 = csr[i], s1 = csr[i + 1], s2 = csr[i + 2], s3 = csr[i + 3];
    float a0 = als[s0 * 8 + head];
    float a1 = als[s1 * 8 + head];
    float a2 = als[s2 * 8 + head];
    float a3 = als[s3 * 8 + head];
    Half4 q0 = *(const Half4*)&hh[(size_t)s0 * 256 + lane * 4];
    Half4 q1 = *(const Half4*)&hh[(size_t)s1 * 256 + lane * 4];
    Half4 q2 = *(const Half4*)&hh[(size_t)s2 * 256 + lane * 4];
    Half4 q3 = *(const Half4*)&hh[(size_t)s3 * 256 + lane * 4];
    float wa = expf(lrelu(a0 + ad));
    float wb = expf(lrelu(a1 + ad));
    float wc = expf(lrelu(a2 + ad));
    float wd = expf(lrelu(a3 + ad));
    float2 l0 = __half22float2(q0.lo), m0 = __half22float2(q0.hi);
    float2 l1 = __half22float2(q1.lo), m1 = __half22float2(q1.hi);
    float2 l2 = __half22float2(q2.lo), m2 = __half22float2(q2.hi);
    float2 l3 = __half22float2(q3.lo), m3 = __half22float2(q3.hi);
    acc.x = fmaf(wa, l0.x, acc.x); acc.y = fmaf(wa, l0.y, acc.y);
    acc.z = fmaf(wa, m0.x, acc.z); acc.w = fmaf(wa, m0.y, acc.w);
    acc.x = fmaf(wb, l1.x, acc.x); acc.y = fmaf(wb, l1.y, acc.y);
    acc.z = fmaf(wb, m1.x, acc.z); acc.w = fmaf(wb, m1.y, acc.w);
    acc.x = fmaf(wc, l2.x, acc.x); acc.y = fmaf(wc, l2.y, acc.y);
    acc.z = fmaf(wc, m2.x, acc.z); acc.w = fmaf(wc, m2.y, acc.w);
    acc.x = fmaf(wd, l3.x, acc.x); acc.y = fmaf(wd, l3.y, acc.y);
    acc.z = fmaf(wd, m3.x, acc.z); acc.w = fmaf(wd, m3.y, acc.w);
    wsum += (wa + wb) + (wc + wd);
  }
  for (; i < end; ++i) {
    int s = csr[i];
    float w = expf(lrelu(als[s * 8 + head] + ad));
    Half4 q0 = *(const Half4*)&hh[(size_t)s * 256 + lane * 4];
    float2 l0 = __half22float2(q0.lo), m0 = __half22float2(q0.hi);
    acc.x = fmaf(w, l0.x, acc.x); acc.y = fmaf(w, l0.y, acc.y);
    acc.z = fmaf(w, m0.x, acc.z); acc.w = fmaf(w, m0.y, acc.w);
    wsum += w;
  }
  float inv = 1.f / (wsum + 1e-16f);
  float4 b = *(const float4*)&bias[lane * 4];
  float4 o;
  o.x = acc.x * inv + b.x; o.y = acc.y * inv + b.y;
  o.z = acc.z * inv + b.z; o.w = acc.w * inv + b.w;
  o.x = o.x > 0.f ? o.x : expm1f(o.x);  // ELU fused
  o.y = o.y > 0.f ? o.y : expm1f(o.y);
  o.z = o.z > 0.f ? o.z : expm1f(o.z);
  o.w = o.w > 0.f ? o.w : expm1f(o.w);
  *(float4*)&outp[(size_t)d * 256 + lane * 4] = o;
}

// ---------------- Layer 2 aggregation: one wave per dst node, 1 float/lane ----------------
__global__ __launch_bounds__(256) void agg2(const float* __restrict__ h,
                                            const float* __restrict__ als, const float* __restrict__ ald,
                                            const int* __restrict__ off, const int* __restrict__ csr,
                                            const float* __restrict__ bias, float* __restrict__ outp, int n) {
  int d = blockIdx.x * 4 + (threadIdx.x >> 6);
  if (d >= n) return;
  int c = threadIdx.x & 63;
  float ad = ald[d];
  float w0 = expf(lrelu(als[d] + ad));
  float acc = w0 * h[(size_t)d * 64 + c];
  float wsum = w0;
  int beg = off[d], end = off[d + 1];
  int i = beg;
  for (; i + 3 < end; i += 4) {
    int s0 = csr[i], s1 = csr[i + 1], s2 = csr[i + 2], s3 = csr[i + 3];
    float a0 = als[s0];
    float a1 = als[s1];
    float a2 = als[s2];
    float a3 = als[s3];
    float h0 = h[(size_t)s0 * 64 + c];
    float h1 = h[(size_t)s1 * 64 + c];
    float h2 = h[(size_t)s2 * 64 + c];
    float h3 = h[(size_t)s3 * 64 + c];
    float wa = expf(lrelu(a0 + ad));
    float wb = expf(lrelu(a1 + ad));
    float wc = expf(lrelu(a2 + ad));
    float wd = expf(lrelu(a3 + ad));
    acc = fmaf(wa, h0, acc);
    acc = fmaf(wb, h1, acc);
    acc = fmaf(wc, h2, acc);
    acc = fmaf(wd, h3, acc);
    wsum += (wa + wb) + (wc + wd);
  }
  for (; i < end; ++i) {
    int s = csr[i];
    float w = expf(lrelu(als[s] + ad));
    acc = fmaf(w, h[(size_t)s * 64 + c], acc);
    wsum += w;
  }
  outp[(size_t)d * 64 + c] = acc / (wsum + 1e-16f) + bias[c];  // heads=1 -> mean is identity
}

extern "C" void kernel_launch(void* const* d_in, const int* in_sizes, int n_in,
                              void* d_out, int out_size, void* d_ws, size_t ws_size,
                              hipStream_t stream) {
  const float* x  = (const float*)d_in[0];
  const int* ei   = (const int*)d_in[1];
  const float* W1 = (const float*)d_in[2];
  const float* a1s = (const float*)d_in[3];
  const float* a1d = (const float*)d_in[4];
  const float* b1  = (const float*)d_in[5];
  const float* W2  = (const float*)d_in[6];
  const float* a2s = (const float*)d_in[7];
  const float* a2d = (const float*)d_in[8];
  const float* b2  = (const float*)d_in[9];
  float* outp = (float*)d_out;

  int n = in_sizes[0] / 128;   // 50000
  int E = in_sizes[1] / 2;     // 640000
  const int* srcv = ei;
  const int* dstv = ei + E;

  char* wsb = (char*)d_ws;
  size_t p = 0;
  auto alloc = [&](size_t bytes) -> char* {
    char* r = wsb + p;
    p += (bytes + 511) & ~size_t(511);
    return r;
  };
  int* deg  = (int*)alloc((size_t)n * 4);
  int* off  = (int*)alloc(((size_t)n + 1) * 4);
  int* cur  = (int*)alloc((size_t)n * 4);
  int* bsum = (int*)alloc(1024);
  int* csr  = (int*)alloc((size_t)E * 4);
  float* h1   = (float*)alloc((size_t)n * 256 * 4);
  __half* h1h = (__half*)alloc((size_t)n * 256 * 2);
  float* al1s = (float*)alloc((size_t)n * 8 * 4);
  float* al1d = (float*)alloc((size_t)n * 8 * 4);
  float* o1   = (float*)alloc((size_t)n * 256 * 4);
  float* h2   = (float*)alloc((size_t)n * 64 * 4);
  float* al2s = (float*)alloc((size_t)n * 4);
  float* al2d = (float*)alloc((size_t)n * 4);
  (void)ws_size;

  hipMemsetAsync(deg, 0, (size_t)n * 4, stream);
  int eb = (E + 255) / 256;
  int nb = (n + 255) / 256;
  count_deg<<<eb, 256, 0, stream>>>(dstv, deg, E);
  scan_partial<<<nb, 256, 0, stream>>>(deg, off, bsum, n);
  scan_bsum<<<1, 256, 0, stream>>>(bsum, off, nb);
  add_carry<<<nb, 256, 0, stream>>>(deg, off, bsum, cur, n);
  fill_csr<<<eb, 256, 0, stream>>>(srcv, dstv, cur, csr, E);

  gemm1<<<(n + 63) / 64, 256, 0, stream>>>(x, W1, h1, h1h, n);
  logits1<<<(n + 3) / 4, 256, 0, stream>>>(h1, a1s, a1d, al1s, al1d, n);
  agg1<<<(n + 3) / 4, 256, 0, stream>>>(h1h, al1s, al1d, off, csr, b1, o1, n);
  gemm2<<<(n + 127) / 128, 256, 0, stream>>>(o1, W2, h2, n);
  logits2<<<(n + 3) / 4, 256, 0, stream>>>(h2, a2s, a2d, al2s, al2d, n);
  agg2<<<(n + 3) / 4, 256, 0, stream>>>(h2, al2s, al2d, off, csr, b2, outp, n);
}

// Round 16
// 368.087 us; speedup vs baseline: 1.9510x; 1.0007x over previous
//
#include <hip/hip_runtime.h>
#include <hip/hip_fp16.h>

// GAT 2-layer forward for MI355X.
//  - CSR build (histogram + scan + fill), once per call.
//  - Register-tiled f32 GEMMs (8x8 / 8x4 per thread, k-chunk 32) with the
//    attention logits fused into the epilogue (shfl-reduce over the lane group
//    that owns each row×head) — kills the h1-f32 write + logits re-read.
//  - gemm1 emits ONLY a packed-fp16 h1 (agg1's random-gather path measured
//    BW-bound ~3.8 TB/s; fp16 halves gathered bytes).
//  - Aggregation: wave-per-node, inline wave-parallel exp, 4-way pipelined
//    edge loop. Softmax normalization folded to a final divide
//    (max-subtraction omitted: shift-invariant, logits bounded ~|8|).

static __device__ __forceinline__ float lrelu(float x) { return x > 0.f ? x : 0.2f * x; }

struct alignas(8) Half4 { __half2 lo, hi; };

// ---------------- CSR build ----------------
__global__ void count_deg(const int* __restrict__ dstv, int* __restrict__ deg, int E) {
  int e = blockIdx.x * blockDim.x + threadIdx.x;
  if (e < E) atomicAdd(&deg[dstv[e]], 1);
}

__global__ void scan_partial(const int* __restrict__ deg, int* __restrict__ off,
                             int* __restrict__ bsum, int n) {
  int tid = threadIdx.x;
  int i = blockIdx.x * 256 + tid;
  int v = (i < n) ? deg[i] : 0;
  int lane = tid & 63, w = tid >> 6;
  int sv = v;
#pragma unroll
  for (int o = 1; o < 64; o <<= 1) {
    int t = __shfl_up(sv, o);
    if (lane >= o) sv += t;
  }
  __shared__ int ws[4];
  if (lane == 63) ws[w] = sv;
  __syncthreads();
  int add = 0;
  for (int j = 0; j < w; ++j) add += ws[j];
  sv += add;
  if (i < n) off[i + 1] = sv;
  if (tid == 255) bsum[blockIdx.x] = sv;
}

__global__ void scan_bsum(int* __restrict__ bsum, int* __restrict__ off, int nb) {
  int tid = threadIdx.x;  // 256 threads; requires nb <= 256 (N=50000 -> nb=196)
  int v = (tid < nb) ? bsum[tid] : 0;
  int lane = tid & 63, w = tid >> 6;
  int sv = v;
#pragma unroll
  for (int o = 1; o < 64; o <<= 1) {
    int t = __shfl_up(sv, o);
    if (lane >= o) sv += t;
  }
  __shared__ int ws[4];
  if (lane == 63) ws[w] = sv;
  __syncthreads();
  int add = 0;
  for (int j = 0; j < w; ++j) add += ws[j];
  sv += add;
  if (tid < nb) bsum[tid] = sv - v;  // exclusive prefix of block sums
  if (tid == 0) off[0] = 0;
}

__global__ void add_carry(const int* __restrict__ deg, int* __restrict__ off,
                          const int* __restrict__ bsum, int* __restrict__ cur, int n) {
  int i = blockIdx.x * 256 + threadIdx.x;
  if (i < n) {
    int o = off[i + 1] + bsum[blockIdx.x];
    off[i + 1] = o;
    cur[i] = o - deg[i];  // = off[i]
  }
}

__global__ void fill_csr(const int* __restrict__ srcv, const int* __restrict__ dstv,
                         int* __restrict__ cur, int* __restrict__ csr, int E) {
  int e = blockIdx.x * blockDim.x + threadIdx.x;
  if (e < E) {
    int p = atomicAdd(&cur[dstv[e]], 1);
    csr[p] = srcv[e];
  }
}

// ---------------- GEMM1: [n,128] x [128,256] -> h1h (fp16) + fused logits ----------------
__global__ __launch_bounds__(256) void gemm1(const float* __restrict__ x, const float* __restrict__ W,
                                             const float* __restrict__ a_src, const float* __restrict__ a_dst,
                                             __half* __restrict__ hh, float* __restrict__ als,
                                             float* __restrict__ ald, int n) {
  __shared__ float xs[32][64];   // transposed: xs[k][row]; read=broadcast b128, write bank=row (free)
  __shared__ float Ws[32][256];  // Ws[k][col]; read b32 one-lane-per-bank (free)
  int tid = threadIdx.x;
  int tc = tid & 31;        // owns cols tc + 32*j, j=0..7 (one col per head j)
  int tr = tid >> 5;        // owns rows r0 + tr*8 .. +7
  int lr = tid & 63, lj = tid >> 6;  // x-stage coords
  int r0 = blockIdx.x * 64;

  // per-head attention coefficients for this thread's channel tc
  float asv[8], adv[8];
#pragma unroll
  for (int j = 0; j < 8; ++j) {
    asv[j] = a_src[j * 32 + tc];
    adv[j] = a_dst[j * 32 + tc];
  }

  float acc[8][8];
#pragma unroll
  for (int r = 0; r < 8; ++r)
#pragma unroll
    for (int j = 0; j < 8; ++j) acc[r][j] = 0.f;

  for (int k0 = 0; k0 < 128; k0 += 32) {
    __syncthreads();
    // stage x chunk: 64 rows x 32 k
    {
      int rr = r0 + lr;
      float4 v0 = {0, 0, 0, 0}, v1 = {0, 0, 0, 0};
      if (rr < n) {
        const float* p = x + (size_t)rr * 128 + k0 + lj * 8;
        v0 = *(const float4*)p;
        v1 = *(const float4*)(p + 4);
      }
      int kk = lj * 8;
      xs[kk + 0][lr] = v0.x; xs[kk + 1][lr] = v0.y; xs[kk + 2][lr] = v0.z; xs[kk + 3][lr] = v0.w;
      xs[kk + 4][lr] = v1.x; xs[kk + 5][lr] = v1.y; xs[kk + 6][lr] = v1.z; xs[kk + 7][lr] = v1.w;
    }
    // stage W chunk: 32 x 256 floats, flat float4 copy
    {
      const float4* src = (const float4*)(W + (size_t)k0 * 256);
      float4* dst = (float4*)&Ws[0][0];
#pragma unroll
      for (int i = tid; i < 2048; i += 256) dst[i] = src[i];
    }
    __syncthreads();
#pragma unroll 4
    for (int k = 0; k < 32; ++k) {
      float xv[8];
      *(float4*)&xv[0] = *(const float4*)&xs[k][tr * 8];
      *(float4*)&xv[4] = *(const float4*)&xs[k][tr * 8 + 4];
      float wv[8];
#pragma unroll
      for (int j = 0; j < 8; ++j) wv[j] = Ws[k][tc + 32 * j];
#pragma unroll
      for (int r = 0; r < 8; ++r)
#pragma unroll
        for (int j = 0; j < 8; ++j) acc[r][j] = fmaf(xv[r], wv[j], acc[r][j]);
    }
  }
#pragma unroll
  for (int r = 0; r < 8; ++r) {
    int row = r0 + tr * 8 + r;
    if (row < n) {
#pragma unroll
      for (int j = 0; j < 8; ++j)
        hh[(size_t)row * 256 + tc + 32 * j] = __float2half(acc[r][j]);
      // fused logits: reduce h[row][head j]*a over the 32 lanes (tc) of this tr-group
#pragma unroll
      for (int j = 0; j < 8; ++j) {
        float vs = acc[r][j] * asv[j];
        float vd = acc[r][j] * adv[j];
#pragma unroll
        for (int o = 16; o >= 1; o >>= 1) {
          vs += __shfl_xor(vs, o);
          vd += __shfl_xor(vd, o);
        }
        if (tc == 0) {
          als[row * 8 + j] = vs;
          ald[row * 8 + j] = vd;
        }
      }
    }
  }
}

// ---------------- GEMM2: [n,256] x [256,64] -> h2 (f32) + fused logits ----------------
__global__ __launch_bounds__(256) void gemm2(const float* __restrict__ xin, const float* __restrict__ W,
                                             const float* __restrict__ a_src, const float* __restrict__ a_dst,
                                             float* __restrict__ h, float* __restrict__ als,
                                             float* __restrict__ ald, int n) {
  __shared__ float xs[32][128];  // transposed
  __shared__ float Ws[32][64];
  int tid = threadIdx.x;
  int tc = tid & 15;  // owns cols tc + 16*j, j=0..3
  int tr = tid >> 4;  // owns rows r0 + tr*8 .. +7 (tr 0..15 -> 128 rows)
  int r0 = blockIdx.x * 128;

  float asv[4], adv[4];
#pragma unroll
  for (int j = 0; j < 4; ++j) {
    asv[j] = a_src[tc + 16 * j];
    adv[j] = a_dst[tc + 16 * j];
  }

  float acc[8][4];
#pragma unroll
  for (int r = 0; r < 8; ++r)
#pragma unroll
    for (int j = 0; j < 4; ++j) acc[r][j] = 0.f;

  for (int k0 = 0; k0 < 256; k0 += 32) {
    __syncthreads();
    // stage x chunk: 128 rows x 32 k  (1024 float4s)
#pragma unroll
    for (int idx = tid; idx < 1024; idx += 256) {
      int r = idx & 127, q = idx >> 7;
      int rr = r0 + r;
      float4 v = {0, 0, 0, 0};
      if (rr < n) v = *(const float4*)(xin + (size_t)rr * 256 + k0 + q * 4);
      int kk = q * 4;
      xs[kk + 0][r] = v.x; xs[kk + 1][r] = v.y; xs[kk + 2][r] = v.z; xs[kk + 3][r] = v.w;
    }
    // stage W chunk: 32 x 64 floats (512 float4s)
    {
      const float4* src = (const float4*)(W + (size_t)k0 * 64);
      float4* dst = (float4*)&Ws[0][0];
#pragma unroll
      for (int i = tid; i < 512; i += 256) dst[i] = src[i];
    }
    __syncthreads();
#pragma unroll 4
    for (int k = 0; k < 32; ++k) {
      float xv[8];
      *(float4*)&xv[0] = *(const float4*)&xs[k][tr * 8];
      *(float4*)&xv[4] = *(const float4*)&xs[k][tr * 8 + 4];
      float wv[4];
#pragma unroll
      for (int j = 0; j < 4; ++j) wv[j] = Ws[k][tc + 16 * j];
#pragma unroll
      for (int r = 0; r < 8; ++r)
#pragma unroll
        for (int j = 0; j < 4; ++j) acc[r][j] = fmaf(xv[r], wv[j], acc[r][j]);
    }
  }
#pragma unroll
  for (int r = 0; r < 8; ++r) {
    int row = r0 + tr * 8 + r;
    if (row < n) {
#pragma unroll
      for (int j = 0; j < 4; ++j) h[(size_t)row * 64 + tc + 16 * j] = acc[r][j];
      // fused logits: in-thread partial over 4 cols, reduce over 16 lanes (tc)
      float vs = acc[r][0] * asv[0];
      float vd = acc[r][0] * adv[0];
#pragma unroll
      for (int j = 1; j < 4; ++j) {
        vs = fmaf(acc[r][j], asv[j], vs);
        vd = fmaf(acc[r][j], adv[j], vd);
      }
#pragma unroll
      for (int o = 8; o >= 1; o >>= 1) {
        vs += __shfl_xor(vs, o);
        vd += __shfl_xor(vd, o);
      }
      if (tc == 0) {
        als[row] = vs;
        ald[row] = vd;
      }
    }
  }
}

// ---------------- Layer 1 aggregation: one wave per dst node, fp16x4/lane gather ----------------
__global__ __launch_bounds__(256) void agg1(const __half* __restrict__ hh,
                                            const float* __restrict__ als, const float* __restrict__ ald,
                                            const int* __restrict__ off, const int* __restrict__ csr,
                                            const float* __restrict__ bias, float* __restrict__ outp, int n) {
  int d = blockIdx.x * 4 + (threadIdx.x >> 6);
  if (d >= n) return;
  int lane = threadIdx.x & 63;
  int head = lane >> 3;  // 8 lanes (32 channels) per head
  float ad = ald[d * 8 + head];
  // self loop
  float w0 = expf(lrelu(als[d * 8 + head] + ad));
  Half4 qv = *(const Half4*)&hh[(size_t)d * 256 + lane * 4];
  float2 vlo = __half22float2(qv.lo), vhi = __half22float2(qv.hi);
  float4 acc;
  acc.x = w0 * vlo.x; acc.y = w0 * vlo.y; acc.z = w0 * vhi.x; acc.w = w0 * vhi.y;
  float wsum = w0;
  int beg = off[d], end = off[d + 1];
  int i = beg;
  for (; i + 3 < end; i += 4) {
    int s0 = csr[i], s1 = csr[i + 1], s2 = csr[i + 2], s3 = csr[i + 3];
    float a0 = als[s0 * 8 + head];
    float a1 = als[s1 * 8 + head];
    float a2 = als[s2 * 8 + head];
    float a3 = als[s3 * 8 + head];
    Half4 q0 = *(const Half4*)&hh[(size_t)s0 * 256 + lane * 4];
    Half4 q1 = *(const Half4*)&hh[(size_t)s1 * 256 + lane * 4];
    Half4 q2 = *(const Half4*)&hh[(size_t)s2 * 256 + lane * 4];
    Half4 q3 = *(const Half4*)&hh[(size_t)s3 * 256 + lane * 4];
    float wa = expf(lrelu(a0 + ad));
    float wb = expf(lrelu(a1 + ad));
    float wc = expf(lrelu(a2 + ad));
    float wd = expf(lrelu(a3 + ad));
    float2 l0 = __half22float2(q0.lo), m0 = __half22float2(q0.hi);
    float2 l1 = __half22float2(q1.lo), m1 = __half22float2(q1.hi);
    float2 l2 = __half22float2(q2.lo), m2 = __half22float2(q2.hi);
    float2 l3 = __half22float2(q3.lo), m3 = __half22float2(q3.hi);
    acc.x = fmaf(wa, l0.x, acc.x); acc.y = fmaf(wa, l0.y, acc.y);
    acc.z = fmaf(wa, m0.x, acc.z); acc.w = fmaf(wa, m0.y, acc.w);
    acc.x = fmaf(wb, l1.x, acc.x); acc.y = fmaf(wb, l1.y, acc.y);
    acc.z = fmaf(wb, m1.x, acc.z); acc.w = fmaf(wb, m1.y, acc.w);
    acc.x = fmaf(wc, l2.x, acc.x); acc.y = fmaf(wc, l2.y, acc.y);
    acc.z = fmaf(wc, m2.x, acc.z); acc.w = fmaf(wc, m2.y, acc.w);
    acc.x = fmaf(wd, l3.x, acc.x); acc.y = fmaf(wd, l3.y, acc.y);
    acc.z = fmaf(wd, m3.x, acc.z); acc.w = fmaf(wd, m3.y, acc.w);
    wsum += (wa + wb) + (wc + wd);
  }
  for (; i < end; ++i) {
    int s = csr[i];
    float w = expf(lrelu(als[s * 8 + head] + ad));
    Half4 q0 = *(const Half4*)&hh[(size_t)s * 256 + lane * 4];
    float2 l0 = __half22float2(q0.lo), m0 = __half22float2(q0.hi);
    acc.x = fmaf(w, l0.x, acc.x); acc.y = fmaf(w, l0.y, acc.y);
    acc.z = fmaf(w, m0.x, acc.z); acc.w = fmaf(w, m0.y, acc.w);
    wsum += w;
  }
  float inv = 1.f / (wsum + 1e-16f);
  float4 b = *(const float4*)&bias[lane * 4];
  float4 o;
  o.x = acc.x * inv + b.x; o.y = acc.y * inv + b.y;
  o.z = acc.z * inv + b.z; o.w = acc.w * inv + b.w;
  o.x = o.x > 0.f ? o.x : expm1f(o.x);  // ELU fused
  o.y = o.y > 0.f ? o.y : expm1f(o.y);
  o.z = o.z > 0.f ? o.z : expm1f(o.z);
  o.w = o.w > 0.f ? o.w : expm1f(o.w);
  *(float4*)&outp[(size_t)d * 256 + lane * 4] = o;
}

// ---------------- Layer 2 aggregation: one wave per dst node, 1 float/lane ----------------
__global__ __launch_bounds__(256) void agg2(const float* __restrict__ h,
                                            const float* __restrict__ als, const float* __restrict__ ald,
                                            const int* __restrict__ off, const int* __restrict__ csr,
                                            const float* __restrict__ bias, float* __restrict__ outp, int n) {
  int d = blockIdx.x * 4 + (threadIdx.x >> 6);
  if (d >= n) return;
  int c = threadIdx.x & 63;
  float ad = ald[d];
  float w0 = expf(lrelu(als[d] + ad));
  float acc = w0 * h[(size_t)d * 64 + c];
  float wsum = w0;
  int beg = off[d], end = off[d + 1];
  int i = beg;
  for (; i + 3 < end; i += 4) {
    int s0 = csr[i], s1 = csr[i + 1], s2 = csr[i + 2], s3 = csr[i + 3];
    float a0 = als[s0];
    float a1 = als[s1];
    float a2 = als[s2];
    float a3 = als[s3];
    float h0 = h[(size_t)s0 * 64 + c];
    float h1 = h[(size_t)s1 * 64 + c];
    float h2 = h[(size_t)s2 * 64 + c];
    float h3 = h[(size_t)s3 * 64 + c];
    float wa = expf(lrelu(a0 + ad));
    float wb = expf(lrelu(a1 + ad));
    float wc = expf(lrelu(a2 + ad));
    float wd = expf(lrelu(a3 + ad));
    acc = fmaf(wa, h0, acc);
    acc = fmaf(wb, h1, acc);
    acc = fmaf(wc, h2, acc);
    acc = fmaf(wd, h3, acc);
    wsum += (wa + wb) + (wc + wd);
  }
  for (; i < end; ++i) {
    int s = csr[i];
    float w = expf(lrelu(als[s] + ad));
    acc = fmaf(w, h[(size_t)s * 64 + c], acc);
    wsum += w;
  }
  outp[(size_t)d * 64 + c] = acc / (wsum + 1e-16f) + bias[c];  // heads=1 -> mean is identity
}

extern "C" void kernel_launch(void* const* d_in, const int* in_sizes, int n_in,
                              void* d_out, int out_size, void* d_ws, size_t ws_size,
                              hipStream_t stream) {
  const float* x  = (const float*)d_in[0];
  const int* ei   = (const int*)d_in[1];
  const float* W1 = (const float*)d_in[2];
  const float* a1s = (const float*)d_in[3];
  const float* a1d = (const float*)d_in[4];
  const float* b1  = (const float*)d_in[5];
  const float* W2  = (const float*)d_in[6];
  const float* a2s = (const float*)d_in[7];
  const float* a2d = (const float*)d_in[8];
  const float* b2  = (const float*)d_in[9];
  float* outp = (float*)d_out;

  int n = in_sizes[0] / 128;   // 50000
  int E = in_sizes[1] / 2;     // 640000
  const int* srcv = ei;
  const int* dstv = ei + E;

  char* wsb = (char*)d_ws;
  size_t p = 0;
  auto alloc = [&](size_t bytes) -> char* {
    char* r = wsb + p;
    p += (bytes + 511) & ~size_t(511);
    return r;
  };
  int* deg  = (int*)alloc((size_t)n * 4);
  int* off  = (int*)alloc(((size_t)n + 1) * 4);
  int* cur  = (int*)alloc((size_t)n * 4);
  int* bsum = (int*)alloc(1024);
  int* csr  = (int*)alloc((size_t)E * 4);
  __half* h1h = (__half*)alloc((size_t)n * 256 * 2);
  float* al1s = (float*)alloc((size_t)n * 8 * 4);
  float* al1d = (float*)alloc((size_t)n * 8 * 4);
  float* o1   = (float*)alloc((size_t)n * 256 * 4);
  float* h2   = (float*)alloc((size_t)n * 64 * 4);
  float* al2s = (float*)alloc((size_t)n * 4);
  float* al2d = (float*)alloc((size_t)n * 4);
  (void)ws_size;

  hipMemsetAsync(deg, 0, (size_t)n * 4, stream);
  int eb = (E + 255) / 256;
  int nb = (n + 255) / 256;
  count_deg<<<eb, 256, 0, stream>>>(dstv, deg, E);
  scan_partial<<<nb, 256, 0, stream>>>(deg, off, bsum, n);
  scan_bsum<<<1, 256, 0, stream>>>(bsum, off, nb);
  add_carry<<<nb, 256, 0, stream>>>(deg, off, bsum, cur, n);
  fill_csr<<<eb, 256, 0, stream>>>(srcv, dstv, cur, csr, E);

  gemm1<<<(n + 63) / 64, 256, 0, stream>>>(x, W1, a1s, a1d, h1h, al1s, al1d, n);
  agg1<<<(n + 3) / 4, 256, 0, stream>>>(h1h, al1s, al1d, off, csr, b1, o1, n);
  gemm2<<<(n + 127) / 128, 256, 0, stream>>>(o1, W2, a2s, a2d, h2, al2s, al2d, n);
  agg2<<<(n + 3) / 4, 256, 0, stream>>>(h2, al2s, al2d, off, csr, b2, outp, n);
}